// Round 1
// baseline (29208.066 us; speedup 1.0000x reference)
//
#include <hip/hip_runtime.h>
#include <hip/hip_bf16.h>

// Model dims (fixed by reference)
#define LL 8
#define DD 1024
#define HH 16
#define DHH 64
#define SS 1024
#define BB 4
#define VV 32000
#define MM (BB * SS)   // 4096 rows

// ---------------------------------------------------------------------------
// Embedding: x[b,s,:] = tok_emb[idx[b,s],:] + pos_emb[s,:]
// ---------------------------------------------------------------------------
__global__ __launch_bounds__(256) void embed_kernel(
    const int* __restrict__ idx, const float* __restrict__ tok,
    const float* __restrict__ pos, float* __restrict__ x) {
  int i = blockIdx.x * blockDim.x + threadIdx.x;  // one float4 per thread
  int elem = i * 4;
  int row = elem / DD;         // b*S + s
  int d = elem % DD;
  int s = row % SS;
  int t = idx[row];
  float4 tv = *(const float4*)(tok + (size_t)t * DD + d);
  float4 pv = *(const float4*)(pos + (size_t)s * DD + d);
  tv.x += pv.x; tv.y += pv.y; tv.z += pv.z; tv.w += pv.w;
  *(float4*)(x + (size_t)elem) = tv;
}

// ---------------------------------------------------------------------------
// LayerNorm over D=1024: one block (256 thr) per row, 4 elems/thread
// ---------------------------------------------------------------------------
__global__ __launch_bounds__(256) void ln_kernel(
    const float* __restrict__ x, const float* __restrict__ sc,
    const float* __restrict__ bi, float* __restrict__ out) {
  const int row = blockIdx.x;
  const int tid = threadIdx.x;
  __shared__ float red[4];
  float4 v = ((const float4*)(x + (size_t)row * DD))[tid];
  float s = v.x + v.y + v.z + v.w;
  #pragma unroll
  for (int off = 32; off; off >>= 1) s += __shfl_down(s, off);
  if ((tid & 63) == 0) red[tid >> 6] = s;
  __syncthreads();
  float mean = (red[0] + red[1] + red[2] + red[3]) * (1.f / DD);
  float dx = v.x - mean, dy = v.y - mean, dz = v.z - mean, dw = v.w - mean;
  float vs = dx * dx + dy * dy + dz * dz + dw * dw;
  __syncthreads();  // red reuse
  #pragma unroll
  for (int off = 32; off; off >>= 1) vs += __shfl_down(vs, off);
  if ((tid & 63) == 0) red[tid >> 6] = vs;
  __syncthreads();
  float var = (red[0] + red[1] + red[2] + red[3]) * (1.f / DD);
  float rstd = rsqrtf(var + 1e-5f);
  float4 s4 = ((const float4*)sc)[tid];
  float4 b4 = ((const float4*)bi)[tid];
  float4 o;
  o.x = dx * rstd * s4.x + b4.x;
  o.y = dy * rstd * s4.y + b4.y;
  o.z = dz * rstd * s4.z + b4.z;
  o.w = dw * rstd * s4.w + b4.w;
  ((float4*)(out + (size_t)row * DD))[tid] = o;
}

// ---------------------------------------------------------------------------
// Tiled fp32 GEMM: C[M,N] = A[M,K] @ B[K,N] (+bias)(+relu)(+resid)
// HEADW: B is [H][K][64] blocks; BN=64 tile == one head (QKV weights)
// 64x64 tile, BK=16, 256 threads, 4x4 micro-tile
// ---------------------------------------------------------------------------
template <bool HEADW, bool BIAS, bool RELU, bool RESID>
__global__ __launch_bounds__(256) void gemm_kernel(
    const float* __restrict__ A, const float* __restrict__ Bw,
    const float* __restrict__ bias, const float* __restrict__ resid,
    float* __restrict__ C, int M, int N, int K) {
  __shared__ alignas(16) float As[16][68];
  __shared__ alignas(16) float Bs[16][68];
  const int tid = threadIdx.x;
  const int tx = tid & 15, ty = tid >> 4;
  const int m0 = blockIdx.y * 64, n0 = blockIdx.x * 64;
  const float* Bbase = HEADW ? (Bw + (size_t)(n0 >> 6) * K * 64) : (Bw + n0);
  const int ldb = HEADW ? 64 : N;
  const int ar = tid >> 2;         // A row in tile (0..63)
  const int ac = (tid & 3) * 4;    // A k-offset (0,4,8,12)
  const int br = tid >> 4;         // B k row (0..15)
  const int bc = (tid & 15) * 4;   // B col (0..60)
  float acc[4][4] = {};
  for (int k0 = 0; k0 < K; k0 += 16) {
    float4 av = *(const float4*)(A + (size_t)(m0 + ar) * K + k0 + ac);
    float4 bv = *(const float4*)(Bbase + (size_t)(k0 + br) * ldb + bc);
    As[ac + 0][ar] = av.x;
    As[ac + 1][ar] = av.y;
    As[ac + 2][ar] = av.z;
    As[ac + 3][ar] = av.w;
    *(float4*)&Bs[br][bc] = bv;
    __syncthreads();
    #pragma unroll
    for (int kk = 0; kk < 16; ++kk) {
      float4 a = *(const float4*)&As[kk][ty * 4];
      float4 b = *(const float4*)&Bs[kk][tx * 4];
      acc[0][0] += a.x * b.x; acc[0][1] += a.x * b.y; acc[0][2] += a.x * b.z; acc[0][3] += a.x * b.w;
      acc[1][0] += a.y * b.x; acc[1][1] += a.y * b.y; acc[1][2] += a.y * b.z; acc[1][3] += a.y * b.w;
      acc[2][0] += a.z * b.x; acc[2][1] += a.z * b.y; acc[2][2] += a.z * b.z; acc[2][3] += a.z * b.w;
      acc[3][0] += a.w * b.x; acc[3][1] += a.w * b.y; acc[3][2] += a.w * b.z; acc[3][3] += a.w * b.w;
    }
    __syncthreads();
  }
  #pragma unroll
  for (int i = 0; i < 4; ++i) {
    const int m = m0 + ty * 4 + i;
    #pragma unroll
    for (int j = 0; j < 4; ++j) {
      const int n = n0 + tx * 4 + j;
      float v = acc[i][j];
      if (BIAS) v += bias[n];
      if (RELU) v = fmaxf(v, 0.f);
      if (RESID) v += resid[(size_t)m * N + n];
      C[(size_t)m * N + n] = v;
    }
  }
}

// ---------------------------------------------------------------------------
// Attention: one block (256 thr) per (b,h,s) query row.
// q/k/v layout: [B, S, H, DH]  (row-major [M][H*DH] from the QKV GEMM)
// ---------------------------------------------------------------------------
__global__ __launch_bounds__(256) void attn_kernel(
    const float* __restrict__ q, const float* __restrict__ k,
    const float* __restrict__ v, float* __restrict__ o) {
  const int s = blockIdx.x;
  const int h = blockIdx.y;
  const int b = blockIdx.z;
  const int tid = threadIdx.x;
  __shared__ float qs[64];
  __shared__ float scx[SS];
  __shared__ float red[4];
  __shared__ float part[4][64];

  const float* qrow = q + (((size_t)b * SS + s) * HH + h) * DHH;
  if (tid < 64) qs[tid] = qrow[tid];
  __syncthreads();

  const float* kb = k + ((size_t)b * SS * HH + h) * DHH;  // + t*(H*DH) + e
  float lmax = -1e30f;
  for (int t = tid; t <= s; t += 256) {
    const float* kr = kb + (size_t)t * (HH * DHH);
    float d = 0.f;
    #pragma unroll
    for (int e = 0; e < DHH; e += 4) {
      float4 kv = *(const float4*)(kr + e);
      float4 qv = *(const float4*)(qs + e);
      d += qv.x * kv.x + qv.y * kv.y + qv.z * kv.z + qv.w * kv.w;
    }
    d *= 0.125f;  // DH^-0.5
    scx[t] = d;
    lmax = fmaxf(lmax, d);
  }
  #pragma unroll
  for (int off = 32; off; off >>= 1) lmax = fmaxf(lmax, __shfl_down(lmax, off));
  if ((tid & 63) == 0) red[tid >> 6] = lmax;
  __syncthreads();
  const float m = fmaxf(fmaxf(red[0], red[1]), fmaxf(red[2], red[3]));

  float lsum = 0.f;
  for (int t = tid; t <= s; t += 256) {
    float p = expf(scx[t] - m);
    scx[t] = p;
    lsum += p;
  }
  __syncthreads();  // all scx exp'd + red max reads done
  #pragma unroll
  for (int off = 32; off; off >>= 1) lsum += __shfl_down(lsum, off);
  if ((tid & 63) == 0) red[tid >> 6] = lsum;
  __syncthreads();
  const float inv = 1.f / (red[0] + red[1] + red[2] + red[3]);

  const int e = tid & 63, c = tid >> 6;
  const float* vb = v + ((size_t)b * SS * HH + h) * DHH + e;
  float acc = 0.f;
  for (int t = c; t <= s; t += 4) acc += scx[t] * vb[(size_t)t * (HH * DHH)];
  part[c][e] = acc;
  __syncthreads();
  if (tid < 64) {
    float r = (part[0][e] + part[1][e] + part[2][e] + part[3][e]) * inv;
    o[(((size_t)b * SS + s) * HH + h) * DHH + e] = r;
  }
}

// ---------------------------------------------------------------------------
extern "C" void kernel_launch(void* const* d_in, const int* in_sizes, int n_in,
                              void* d_out, int out_size, void* d_ws, size_t ws_size,
                              hipStream_t stream) {
  const int* idx = (const int*)d_in[0];
  const float* tok_emb = (const float*)d_in[1];
  const float* pos_emb = (const float*)d_in[2];
  const float* ln1_s = (const float*)d_in[3];
  const float* ln1_b = (const float*)d_in[4];
  const float* wq = (const float*)d_in[5];
  const float* wk = (const float*)d_in[6];
  const float* wv = (const float*)d_in[7];
  const float* wproj = (const float*)d_in[8];
  const float* ln2_s = (const float*)d_in[9];
  const float* ln2_b = (const float*)d_in[10];
  const float* w1 = (const float*)d_in[11];
  const float* b1 = (const float*)d_in[12];
  const float* w2 = (const float*)d_in[13];
  const float* b2 = (const float*)d_in[14];
  const float* lnf_s = (const float*)d_in[15];
  const float* lnf_b = (const float*)d_in[16];
  const float* lm_w = (const float*)d_in[17];
  const float* lm_b = (const float*)d_in[18];

  // Scratch layout:
  //   d_ws:  x (M*D), h (M*D)          -> 32 MB
  //   d_out: q,k,v,o (4 * M*D) overlapped with tmp (M*4D) -> 64 MB of 524 MB;
  //          final LM-head GEMM reads only h (in d_ws) and overwrites all of d_out.
  float* x = (float*)d_ws;
  float* h = x + (size_t)MM * DD;
  float* qb = (float*)d_out;
  float* kb = qb + (size_t)MM * DD;
  float* vb = kb + (size_t)MM * DD;
  float* ob = vb + (size_t)MM * DD;
  float* tmp = qb;  // MLP scratch (M x 4D) reuses q/k/v/o region (dead by then)

  const dim3 blk(256);

  // Embedding
  embed_kernel<<<(MM * DD / 4 + 255) / 256, blk, 0, stream>>>(idx, tok_emb, pos_emb, x);

  for (int l = 0; l < LL; ++l) {
    const size_t wqkv_off = (size_t)l * HH * DD * DHH;  // = l * 1M
    // LN1
    ln_kernel<<<MM, blk, 0, stream>>>(x, ln1_s + l * DD, ln1_b + l * DD, h);
    // QKV (head-blocked weights)
    gemm_kernel<true, false, false, false><<<dim3(DD / 64, MM / 64), blk, 0, stream>>>(
        h, wq + wqkv_off, nullptr, nullptr, qb, MM, DD, DD);
    gemm_kernel<true, false, false, false><<<dim3(DD / 64, MM / 64), blk, 0, stream>>>(
        h, wk + wqkv_off, nullptr, nullptr, kb, MM, DD, DD);
    gemm_kernel<true, false, false, false><<<dim3(DD / 64, MM / 64), blk, 0, stream>>>(
        h, wv + wqkv_off, nullptr, nullptr, vb, MM, DD, DD);
    // Attention
    attn_kernel<<<dim3(SS, HH, BB), blk, 0, stream>>>(qb, kb, vb, ob);
    // Projection + residual (in-place on x)
    gemm_kernel<false, false, false, true><<<dim3(DD / 64, MM / 64), blk, 0, stream>>>(
        ob, wproj + (size_t)l * DD * DD, nullptr, x, x, MM, DD, DD);
    // LN2
    ln_kernel<<<MM, blk, 0, stream>>>(x, ln2_s + l * DD, ln2_b + l * DD, h);
    // MLP
    gemm_kernel<false, true, true, false><<<dim3(4 * DD / 64, MM / 64), blk, 0, stream>>>(
        h, w1 + (size_t)l * DD * 4 * DD, b1 + (size_t)l * 4 * DD, nullptr, tmp,
        MM, 4 * DD, DD);
    gemm_kernel<false, true, false, true><<<dim3(DD / 64, MM / 64), blk, 0, stream>>>(
        tmp, w2 + (size_t)l * 4 * DD * DD, b2 + (size_t)l * DD, x, x, MM, DD, 4 * DD);
  }

  // Final LN + LM head
  ln_kernel<<<MM, blk, 0, stream>>>(x, lnf_s, lnf_b, h);
  gemm_kernel<false, true, false, false><<<dim3(VV / 64, MM / 64), blk, 0, stream>>>(
      h, lm_w, lm_b, nullptr, (float*)d_out, MM, VV, DD);
}

// Round 2
// 6402.756 us; speedup vs baseline: 4.5618x; 4.5618x over previous
//
#include <hip/hip_runtime.h>
#include <hip/hip_bf16.h>

// Model dims (fixed by reference)
#define LL 8
#define DD 1024
#define HH 16
#define DHH 64
#define SS 1024
#define BB 4
#define VV 32000
#define MM (BB * SS)   // 4096 rows

typedef unsigned short u16;
typedef __attribute__((ext_vector_type(8))) short short8v;   // 8 bf16 (4 VGPRs)
typedef __attribute__((ext_vector_type(4))) float f32x4;
typedef unsigned int __attribute__((address_space(1))) guint;
typedef unsigned int __attribute__((address_space(3))) luint;

__device__ __forceinline__ float bf2f_lo(unsigned u) { return __uint_as_float(u << 16); }
__device__ __forceinline__ float bf2f_hi(unsigned u) { return __uint_as_float(u & 0xffff0000u); }
__device__ __forceinline__ u16 f2bf(float f) {
  unsigned x = __float_as_uint(f);
  return (u16)((x + 0x7fffu + ((x >> 16) & 1u)) >> 16);
}
__device__ __forceinline__ void unpack8(uint4 u, float* f) {
  f[0] = bf2f_lo(u.x); f[1] = bf2f_hi(u.x);
  f[2] = bf2f_lo(u.y); f[3] = bf2f_hi(u.y);
  f[4] = bf2f_lo(u.z); f[5] = bf2f_hi(u.z);
  f[6] = bf2f_lo(u.w); f[7] = bf2f_hi(u.w);
}

// ---------------------------------------------------------------------------
// Embedding: x[b,s,:] = tok_emb[idx[b,s],:] + pos_emb[s,:]  (fp32 out)
// ---------------------------------------------------------------------------
__global__ __launch_bounds__(256) void embed_kernel(
    const int* __restrict__ idx, const float* __restrict__ tok,
    const float* __restrict__ pos, float* __restrict__ x) {
  int i = blockIdx.x * blockDim.x + threadIdx.x;
  int elem = i * 4;
  int row = elem / DD;
  int d = elem % DD;
  int s = row % SS;
  int t = idx[row];
  float4 tv = *(const float4*)(tok + (size_t)t * DD + d);
  float4 pv = *(const float4*)(pos + (size_t)s * DD + d);
  tv.x += pv.x; tv.y += pv.y; tv.z += pv.z; tv.w += pv.w;
  *(float4*)(x + (size_t)elem) = tv;
}

// ---------------------------------------------------------------------------
// LayerNorm over D=1024 (fp32 in, bf16 out): 1 block / row, 4 elems / thread
// ---------------------------------------------------------------------------
__global__ __launch_bounds__(256) void ln_bf16_kernel(
    const float* __restrict__ x, const float* __restrict__ sc,
    const float* __restrict__ bi, u16* __restrict__ out) {
  const int row = blockIdx.x;
  const int tid = threadIdx.x;
  __shared__ float red[4];
  float4 v = ((const float4*)(x + (size_t)row * DD))[tid];
  float s = v.x + v.y + v.z + v.w;
  #pragma unroll
  for (int off = 32; off; off >>= 1) s += __shfl_down(s, off);
  if ((tid & 63) == 0) red[tid >> 6] = s;
  __syncthreads();
  float mean = (red[0] + red[1] + red[2] + red[3]) * (1.f / DD);
  float dx = v.x - mean, dy = v.y - mean, dz = v.z - mean, dw = v.w - mean;
  float vs = dx * dx + dy * dy + dz * dz + dw * dw;
  __syncthreads();
  #pragma unroll
  for (int off = 32; off; off >>= 1) vs += __shfl_down(vs, off);
  if ((tid & 63) == 0) red[tid >> 6] = vs;
  __syncthreads();
  float var = (red[0] + red[1] + red[2] + red[3]) * (1.f / DD);
  float rstd = rsqrtf(var + 1e-5f);
  float4 s4 = ((const float4*)sc)[tid];
  float4 b4 = ((const float4*)bi)[tid];
  ushort4 o;
  o.x = f2bf(dx * rstd * s4.x + b4.x);
  o.y = f2bf(dy * rstd * s4.y + b4.y);
  o.z = f2bf(dz * rstd * s4.z + b4.z);
  o.w = f2bf(dw * rstd * s4.w + b4.w);
  *(ushort4*)(out + (size_t)row * DD + tid * 4) = o;
}

// ---------------------------------------------------------------------------
// Weight transpose + fp32->bf16: W [l][K][N] (or head-blocked [l][H][K][64])
// -> BT [l][N][K] bf16
// grid (N/32, K/32, L), block 256 (=32x8)
// ---------------------------------------------------------------------------
template <bool HEADW>
__global__ __launch_bounds__(256) void convT_kernel(
    const float* __restrict__ W, u16* __restrict__ BT, int K, int N) {
  __shared__ float tile[32][33];
  const int n0 = blockIdx.x * 32, k0 = blockIdx.y * 32, l = blockIdx.z;
  const int tx = threadIdx.x & 31, ty = threadIdx.x >> 5;
  const float* Wl;
  int ld;
  if (HEADW) {
    const int h = n0 >> 6;
    Wl = W + ((size_t)(l * HH + h) * K) * 64 + (n0 & 63);
    ld = 64;
  } else {
    Wl = W + (size_t)l * K * N + n0;
    ld = N;
  }
  #pragma unroll
  for (int i = 0; i < 4; ++i)
    tile[ty + 8 * i][tx] = Wl[(size_t)(k0 + ty + 8 * i) * ld + tx];
  __syncthreads();
  u16* out = BT + (size_t)l * N * K;
  #pragma unroll
  for (int i = 0; i < 4; ++i)
    out[(size_t)(n0 + ty + 8 * i) * K + k0 + tx] = f2bf(tile[tx][ty + 8 * i]);
}

// ---------------------------------------------------------------------------
// bf16 MFMA GEMM (m97 structure): C[M,N] = A[M,K] @ BT[N,K]^T (+bias)(+relu)(+resid)
// 128x128 tile, BK=64, 256 thr = 4 waves (2x2), 4x4 16x16x32 frags / wave
// ---------------------------------------------------------------------------
template <bool BIAS, bool RELU, bool RESID, bool OBF16>
__global__ __launch_bounds__(256) void gemm_mfma(
    const u16* __restrict__ A, const u16* __restrict__ BT,
    const float* __restrict__ bias, const float* __restrict__ resid,
    void* __restrict__ Cv, int M, int N, int K) {
  __shared__ u16 As[128 * 64];
  __shared__ u16 Bs[128 * 64];
  const int tid = threadIdx.x;
  const int lane = tid & 63, wave = tid >> 6;
  const int m0 = blockIdx.y * 128, n0 = blockIdx.x * 128;
  const int wr = (wave >> 1) * 64, wc = (wave & 1) * 64;
  const int srow = tid >> 3, scol = (tid & 7) * 8;
  const u16* Ag = A + (size_t)(m0 + srow) * K + scol;
  const u16* Bg = BT + (size_t)(n0 + srow) * K + scol;

  f32x4 acc[4][4] = {};
  for (int k0 = 0; k0 < K; k0 += 64) {
    #pragma unroll
    for (int c = 0; c < 4; ++c) {
      __builtin_amdgcn_global_load_lds(
          (const guint*)(Ag + k0 + (size_t)c * 32 * K),
          (luint*)(As + c * 2048 + tid * 8), 16, 0, 0);
      __builtin_amdgcn_global_load_lds(
          (const guint*)(Bg + k0 + (size_t)c * 32 * K),
          (luint*)(Bs + c * 2048 + tid * 8), 16, 0, 0);
    }
    __syncthreads();
    #pragma unroll
    for (int kk = 0; kk < 64; kk += 32) {
      short8v av[4], bv[4];
      #pragma unroll
      for (int i = 0; i < 4; ++i)
        av[i] = *(const short8v*)(As + (wr + i * 16 + (lane & 15)) * 64 + kk + (lane >> 4) * 8);
      #pragma unroll
      for (int j = 0; j < 4; ++j)
        bv[j] = *(const short8v*)(Bs + (wc + j * 16 + (lane & 15)) * 64 + kk + (lane >> 4) * 8);
      #pragma unroll
      for (int i = 0; i < 4; ++i)
        #pragma unroll
        for (int j = 0; j < 4; ++j)
          acc[i][j] = __builtin_amdgcn_mfma_f32_16x16x32_bf16(av[i], bv[j], acc[i][j], 0, 0, 0);
    }
    __syncthreads();
  }
  // epilogue: row = m0+wr+i*16+(lane>>4)*4+r, col = n0+wc+j*16+(lane&15)
  #pragma unroll
  for (int i = 0; i < 4; ++i) {
    #pragma unroll
    for (int j = 0; j < 4; ++j) {
      const int col = n0 + wc + j * 16 + (lane & 15);
      #pragma unroll
      for (int r = 0; r < 4; ++r) {
        const int row = m0 + wr + i * 16 + (lane >> 4) * 4 + r;
        float v = acc[i][j][r];
        if (BIAS) v += bias[col];
        if (RELU) v = fmaxf(v, 0.f);
        if (RESID) v += resid[(size_t)row * N + col];
        if (OBF16)
          ((u16*)Cv)[(size_t)row * N + col] = f2bf(v);
        else
          ((float*)Cv)[(size_t)row * N + col] = v;
      }
    }
  }
}

// ---------------------------------------------------------------------------
// Fallback fp32 GEMM for LM head (A bf16, B fp32 [K][N], +bias) — used only if
// ws is too small to hold the transposed bf16 lm_w.
// ---------------------------------------------------------------------------
__global__ __launch_bounds__(256) void gemm_fb(
    const u16* __restrict__ A, const float* __restrict__ B,
    const float* __restrict__ bias, float* __restrict__ C, int M, int N, int K) {
  __shared__ alignas(16) float As[16][68];
  __shared__ alignas(16) float Bs[16][68];
  const int tid = threadIdx.x;
  const int tx = tid & 15, ty = tid >> 4;
  const int m0 = blockIdx.y * 64, n0 = blockIdx.x * 64;
  const int ar = tid >> 2, ac = (tid & 3) * 4;
  const int br = tid >> 4, bc = (tid & 15) * 4;
  float acc[4][4] = {};
  for (int k0 = 0; k0 < K; k0 += 16) {
    ushort4 au = *(const ushort4*)(A + (size_t)(m0 + ar) * K + k0 + ac);
    float4 bv = *(const float4*)(B + (size_t)(k0 + br) * N + n0 + bc);
    As[ac + 0][ar] = bf2f_lo(au.x);
    As[ac + 1][ar] = bf2f_lo(au.y);
    As[ac + 2][ar] = bf2f_lo(au.z);
    As[ac + 3][ar] = bf2f_lo(au.w);
    *(float4*)&Bs[br][bc] = bv;
    __syncthreads();
    #pragma unroll
    for (int kk = 0; kk < 16; ++kk) {
      float4 a = *(const float4*)&As[kk][ty * 4];
      float4 b = *(const float4*)&Bs[kk][tx * 4];
      acc[0][0] += a.x * b.x; acc[0][1] += a.x * b.y; acc[0][2] += a.x * b.z; acc[0][3] += a.x * b.w;
      acc[1][0] += a.y * b.x; acc[1][1] += a.y * b.y; acc[1][2] += a.y * b.z; acc[1][3] += a.y * b.w;
      acc[2][0] += a.z * b.x; acc[2][1] += a.z * b.y; acc[2][2] += a.z * b.z; acc[2][3] += a.z * b.w;
      acc[3][0] += a.w * b.x; acc[3][1] += a.w * b.y; acc[3][2] += a.w * b.z; acc[3][3] += a.w * b.w;
    }
    __syncthreads();
  }
  #pragma unroll
  for (int i = 0; i < 4; ++i) {
    const int m = m0 + ty * 4 + i;
    #pragma unroll
    for (int j = 0; j < 4; ++j) {
      const int n = n0 + tx * 4 + j;
      C[(size_t)m * N + n] = acc[i][j] + bias[n];
    }
  }
}

// ---------------------------------------------------------------------------
// Tiled flash attention (VALU, bf16 in/out, fp32 math).
// Block = 256 thr, one (b,h, 32-q-row tile). K/V tiles of 64 rows in LDS.
// thread -> (qr = tid>>3, g = tid&7): q-row qr, dim/k-group g.
// ---------------------------------------------------------------------------
#define QB 32
#define KB 64
__global__ __launch_bounds__(256) void attn_tiled(
    const u16* __restrict__ q, const u16* __restrict__ k,
    const u16* __restrict__ v, u16* __restrict__ o) {
  __shared__ float Qs[QB][68];
  __shared__ float Kt[64][68];  // [dim][k-row]
  __shared__ float Vs[64][68];  // [k-row][dim]
  __shared__ float Ps[QB][66];
  const int tid = threadIdx.x;
  const int qt = blockIdx.x, h = blockIdx.y, b = blockIdx.z;
  const int qr = tid >> 3, g = tid & 7;
  const int qrow = qt * QB + qr;
  const size_t HD = (size_t)HH * DHH;  // 1024

  {  // stage Q tile (each thread: its 8 dims of its q-row)
    const u16* qp = q + ((size_t)b * SS + qrow) * HD + h * DHH + g * 8;
    float qf[8];
    unpack8(*(const uint4*)qp, qf);
    #pragma unroll
    for (int e = 0; e < 8; ++e) Qs[qr][g * 8 + e] = qf[e];
  }

  float mrow = -1e30f, lrow = 0.f;
  float Ov[8] = {};
  const int ktmax = (qt * QB + QB - 1) / KB;
  const int skr = tid >> 2;            // staging k-row (0..63)
  const int sd0 = (tid & 3) * 16;      // staging dim offset

  for (int t = 0; t <= ktmax; ++t) {
    __syncthreads();  // protect LDS reuse
    {  // stage K (transposed) and V
      const u16* kp = k + ((size_t)b * SS + t * KB + skr) * HD + h * DHH + sd0;
      float kf[16];
      unpack8(*(const uint4*)kp, kf);
      unpack8(*(const uint4*)(kp + 8), kf + 8);
      #pragma unroll
      for (int e = 0; e < 16; ++e) Kt[sd0 + e][skr] = kf[e];
      const u16* vp = v + ((size_t)b * SS + t * KB + skr) * HD + h * DHH + sd0;
      float vf[16];
      unpack8(*(const uint4*)vp, vf);
      unpack8(*(const uint4*)(vp + 8), vf + 8);
      #pragma unroll
      for (int c = 0; c < 4; ++c)
        *(float4*)&Vs[skr][sd0 + c * 4] = make_float4(vf[c*4], vf[c*4+1], vf[c*4+2], vf[c*4+3]);
    }
    __syncthreads();

    // scores: sc[j] = q[qrow] . k[t*64 + g*8 + j]
    float sc[8] = {};
    #pragma unroll 16
    for (int d = 0; d < 64; ++d) {
      float qv = Qs[qr][d];
      float4 k0v = *(const float4*)&Kt[d][g * 8];
      float4 k1v = *(const float4*)&Kt[d][g * 8 + 4];
      sc[0] += qv * k0v.x; sc[1] += qv * k0v.y; sc[2] += qv * k0v.z; sc[3] += qv * k0v.w;
      sc[4] += qv * k1v.x; sc[5] += qv * k1v.y; sc[6] += qv * k1v.z; sc[7] += qv * k1v.w;
    }
    const int kbase = t * KB + g * 8;
    float mt = -1e30f;
    #pragma unroll
    for (int j = 0; j < 8; ++j) {
      sc[j] = (kbase + j <= qrow) ? sc[j] * 0.125f : -1e30f;
      mt = fmaxf(mt, sc[j]);
    }
    mt = fmaxf(mt, __shfl_xor(mt, 1));
    mt = fmaxf(mt, __shfl_xor(mt, 2));
    mt = fmaxf(mt, __shfl_xor(mt, 4));
    const float mnew = fmaxf(mrow, mt);
    float pl = 0.f;
    #pragma unroll
    for (int j = 0; j < 8; ++j) {
      float p = __expf(sc[j] - mnew);  // masked -> exp(-1e30) = 0
      Ps[qr][g * 8 + j] = p;
      pl += p;
    }
    pl += __shfl_xor(pl, 1);
    pl += __shfl_xor(pl, 2);
    pl += __shfl_xor(pl, 4);
    const float corr = __expf(mrow - mnew);
    lrow = lrow * corr + pl;
    mrow = mnew;
    #pragma unroll
    for (int e = 0; e < 8; ++e) Ov[e] *= corr;

    // PV: Ov[dims g*8..] += sum_kr P[qr][kr] * V[kr][dims]
    // (Ps for row qr written by this wave's own lanes -> no barrier needed)
    #pragma unroll 8
    for (int kr = 0; kr < KB; ++kr) {
      float p = Ps[qr][kr];
      float4 v0 = *(const float4*)&Vs[kr][g * 8];
      float4 v1 = *(const float4*)&Vs[kr][g * 8 + 4];
      Ov[0] += p * v0.x; Ov[1] += p * v0.y; Ov[2] += p * v0.z; Ov[3] += p * v0.w;
      Ov[4] += p * v1.x; Ov[5] += p * v1.y; Ov[6] += p * v1.z; Ov[7] += p * v1.w;
    }
  }
  const float inv = 1.f / lrow;
  uint4 r;
  r.x = (unsigned)f2bf(Ov[0] * inv) | ((unsigned)f2bf(Ov[1] * inv) << 16);
  r.y = (unsigned)f2bf(Ov[2] * inv) | ((unsigned)f2bf(Ov[3] * inv) << 16);
  r.z = (unsigned)f2bf(Ov[4] * inv) | ((unsigned)f2bf(Ov[5] * inv) << 16);
  r.w = (unsigned)f2bf(Ov[6] * inv) | ((unsigned)f2bf(Ov[7] * inv) << 16);
  *(uint4*)(o + ((size_t)b * SS + qrow) * HD + h * DHH + g * 8) = r;
}

// ---------------------------------------------------------------------------
extern "C" void kernel_launch(void* const* d_in, const int* in_sizes, int n_in,
                              void* d_out, int out_size, void* d_ws, size_t ws_size,
                              hipStream_t stream) {
  const int* idx = (const int*)d_in[0];
  const float* tok_emb = (const float*)d_in[1];
  const float* pos_emb = (const float*)d_in[2];
  const float* ln1_s = (const float*)d_in[3];
  const float* ln1_b = (const float*)d_in[4];
  const float* wq = (const float*)d_in[5];
  const float* wk = (const float*)d_in[6];
  const float* wv = (const float*)d_in[7];
  const float* wproj = (const float*)d_in[8];
  const float* ln2_s = (const float*)d_in[9];
  const float* ln2_b = (const float*)d_in[10];
  const float* w1 = (const float*)d_in[11];
  const float* b1 = (const float*)d_in[12];
  const float* w2 = (const float*)d_in[13];
  const float* b2 = (const float*)d_in[14];
  const float* lnf_s = (const float*)d_in[15];
  const float* lnf_b = (const float*)d_in[16];
  const float* lm_w = (const float*)d_in[17];
  const float* lm_b = (const float*)d_in[18];

  const size_t MD = (size_t)MM * DD;  // 4,194,304

  // d_out scratch (524 MB; everything here is dead before the final LM GEMM
  // writes d_out, which reads only from d_ws + inputs):
  u16* sc0 = (u16*)d_out;
  u16* BTq = sc0;                                   // 8 x 1M
  u16* BTk = BTq + (size_t)LL * DD * DD;
  u16* BTv = BTk + (size_t)LL * DD * DD;
  u16* BTp = BTv + (size_t)LL * DD * DD;
  u16* BTw1 = BTp + (size_t)LL * DD * DD;           // 8 x 4M
  u16* BTw2 = BTw1 + (size_t)LL * DD * 4 * DD;      // 8 x 4M
  u16* qb = BTw2 + (size_t)LL * DD * 4 * DD;
  u16* kb = qb + MD;
  u16* vb = kb + MD;
  u16* ob = vb + MD;
  u16* tmp = ob + MD;                               // M x 4D

  // d_ws: x fp32 (16MB) + h bf16 (8MB) [+ BT(lm_w) bf16 (65.5MB) if room]
  float* x = (float*)d_ws;
  u16* h = (u16*)((char*)d_ws + MD * 4);
  u16* BTlm = (u16*)((char*)d_ws + MD * 4 + MD * 2);
  const bool big_ws = ws_size >= (MD * 4 + MD * 2 + (size_t)VV * DD * 2);

  const dim3 blk(256);

  // Weight transpose + convert (per call; deterministic)
  convT_kernel<true><<<dim3(DD / 32, DD / 32, LL), blk, 0, stream>>>(wq, BTq, DD, DD);
  convT_kernel<true><<<dim3(DD / 32, DD / 32, LL), blk, 0, stream>>>(wk, BTk, DD, DD);
  convT_kernel<true><<<dim3(DD / 32, DD / 32, LL), blk, 0, stream>>>(wv, BTv, DD, DD);
  convT_kernel<false><<<dim3(DD / 32, DD / 32, LL), blk, 0, stream>>>(wproj, BTp, DD, DD);
  convT_kernel<false><<<dim3(4 * DD / 32, DD / 32, LL), blk, 0, stream>>>(w1, BTw1, DD, 4 * DD);
  convT_kernel<false><<<dim3(DD / 32, 4 * DD / 32, LL), blk, 0, stream>>>(w2, BTw2, 4 * DD, DD);
  if (big_ws)
    convT_kernel<false><<<dim3(VV / 32, DD / 32, 1), blk, 0, stream>>>(lm_w, BTlm, DD, VV);

  embed_kernel<<<(MM * DD / 4 + 255) / 256, blk, 0, stream>>>(idx, tok_emb, pos_emb, x);

  for (int l = 0; l < LL; ++l) {
    ln_bf16_kernel<<<MM, blk, 0, stream>>>(x, ln1_s + l * DD, ln1_b + l * DD, h);
    gemm_mfma<false, false, false, true><<<dim3(DD / 128, MM / 128), blk, 0, stream>>>(
        h, BTq + (size_t)l * DD * DD, nullptr, nullptr, qb, MM, DD, DD);
    gemm_mfma<false, false, false, true><<<dim3(DD / 128, MM / 128), blk, 0, stream>>>(
        h, BTk + (size_t)l * DD * DD, nullptr, nullptr, kb, MM, DD, DD);
    gemm_mfma<false, false, false, true><<<dim3(DD / 128, MM / 128), blk, 0, stream>>>(
        h, BTv + (size_t)l * DD * DD, nullptr, nullptr, vb, MM, DD, DD);
    attn_tiled<<<dim3(SS / QB, HH, BB), blk, 0, stream>>>(qb, kb, vb, ob);
    gemm_mfma<false, false, true, false><<<dim3(DD / 128, MM / 128), blk, 0, stream>>>(
        ob, BTp + (size_t)l * DD * DD, nullptr, x, x, MM, DD, DD);
    ln_bf16_kernel<<<MM, blk, 0, stream>>>(x, ln2_s + l * DD, ln2_b + l * DD, h);
    gemm_mfma<true, true, false, true><<<dim3(4 * DD / 128, MM / 128), blk, 0, stream>>>(
        h, BTw1 + (size_t)l * DD * 4 * DD, b1 + (size_t)l * 4 * DD, nullptr, tmp,
        MM, 4 * DD, DD);
    gemm_mfma<true, false, true, false><<<dim3(DD / 128, MM / 128), blk, 0, stream>>>(
        tmp, BTw2 + (size_t)l * 4 * DD * DD, b2 + (size_t)l * DD, x, x, MM, DD, 4 * DD);
  }

  ln_bf16_kernel<<<MM, blk, 0, stream>>>(x, lnf_s, lnf_b, h);
  if (big_ws) {
    gemm_mfma<true, false, false, false><<<dim3(VV / 128, MM / 128), blk, 0, stream>>>(
        h, BTlm, lm_b, nullptr, (float*)d_out, MM, VV, DD);
  } else {
    gemm_fb<<<dim3(VV / 64, MM / 64), blk, 0, stream>>>(
        h, lm_w, lm_b, (float*)d_out, MM, VV, DD);
  }
}

// Round 3
// 3319.099 us; speedup vs baseline: 8.8000x; 1.9291x over previous
//
#include <hip/hip_runtime.h>
#include <hip/hip_bf16.h>

// Model dims (fixed by reference)
#define LL 8
#define DD 1024
#define HH 16
#define DHH 64
#define SS 1024
#define BB 4
#define VV 32000
#define MM (BB * SS)   // 4096 rows

typedef unsigned short u16;
typedef __attribute__((ext_vector_type(8))) short short8v;   // 8 bf16 (4 VGPRs)
typedef __attribute__((ext_vector_type(4))) float f32x4;
typedef unsigned int __attribute__((address_space(1))) guint;
typedef unsigned int __attribute__((address_space(3))) luint;

__device__ __forceinline__ float bf2f_lo(unsigned u) { return __uint_as_float(u << 16); }
__device__ __forceinline__ u16 f2bf(float f) {
  unsigned x = __float_as_uint(f);
  return (u16)((x + 0x7fffu + ((x >> 16) & 1u)) >> 16);
}

// ---------------------------------------------------------------------------
// Embedding
// ---------------------------------------------------------------------------
__global__ __launch_bounds__(256) void embed_kernel(
    const int* __restrict__ idx, const float* __restrict__ tok,
    const float* __restrict__ pos, float* __restrict__ x) {
  int i = blockIdx.x * blockDim.x + threadIdx.x;
  int elem = i * 4;
  int row = elem / DD;
  int d = elem % DD;
  int s = row % SS;
  int t = idx[row];
  float4 tv = *(const float4*)(tok + (size_t)t * DD + d);
  float4 pv = *(const float4*)(pos + (size_t)s * DD + d);
  tv.x += pv.x; tv.y += pv.y; tv.z += pv.z; tv.w += pv.w;
  *(float4*)(x + (size_t)elem) = tv;
}

// ---------------------------------------------------------------------------
// LayerNorm over D=1024 (fp32 in, bf16 out)
// ---------------------------------------------------------------------------
__global__ __launch_bounds__(256) void ln_bf16_kernel(
    const float* __restrict__ x, const float* __restrict__ sc,
    const float* __restrict__ bi, u16* __restrict__ out) {
  const int row = blockIdx.x;
  const int tid = threadIdx.x;
  __shared__ float red[4];
  float4 v = ((const float4*)(x + (size_t)row * DD))[tid];
  float s = v.x + v.y + v.z + v.w;
  #pragma unroll
  for (int off = 32; off; off >>= 1) s += __shfl_down(s, off);
  if ((tid & 63) == 0) red[tid >> 6] = s;
  __syncthreads();
  float mean = (red[0] + red[1] + red[2] + red[3]) * (1.f / DD);
  float dx = v.x - mean, dy = v.y - mean, dz = v.z - mean, dw = v.w - mean;
  float vs = dx * dx + dy * dy + dz * dz + dw * dw;
  __syncthreads();
  #pragma unroll
  for (int off = 32; off; off >>= 1) vs += __shfl_down(vs, off);
  if ((tid & 63) == 0) red[tid >> 6] = vs;
  __syncthreads();
  float var = (red[0] + red[1] + red[2] + red[3]) * (1.f / DD);
  float rstd = rsqrtf(var + 1e-5f);
  float4 s4 = ((const float4*)sc)[tid];
  float4 b4 = ((const float4*)bi)[tid];
  ushort4 o;
  o.x = f2bf(dx * rstd * s4.x + b4.x);
  o.y = f2bf(dy * rstd * s4.y + b4.y);
  o.z = f2bf(dz * rstd * s4.z + b4.z);
  o.w = f2bf(dw * rstd * s4.w + b4.w);
  *(ushort4*)(out + (size_t)row * DD + tid * 4) = o;
}

// ---------------------------------------------------------------------------
// Weight transpose + fp32->bf16: W [l][K][N] (or head-blocked) -> BT [l][N][K]
// ---------------------------------------------------------------------------
template <bool HEADW>
__global__ __launch_bounds__(256) void convT_kernel(
    const float* __restrict__ W, u16* __restrict__ BT, int K, int N) {
  __shared__ float tile[32][33];
  const int n0 = blockIdx.x * 32, k0 = blockIdx.y * 32, l = blockIdx.z;
  const int tx = threadIdx.x & 31, ty = threadIdx.x >> 5;
  const float* Wl;
  int ld;
  if (HEADW) {
    const int h = n0 >> 6;
    Wl = W + ((size_t)(l * HH + h) * K) * 64 + (n0 & 63);
    ld = 64;
  } else {
    Wl = W + (size_t)l * K * N + n0;
    ld = N;
  }
  #pragma unroll
  for (int i = 0; i < 4; ++i)
    tile[ty + 8 * i][tx] = Wl[(size_t)(k0 + ty + 8 * i) * ld + tx];
  __syncthreads();
  u16* out = BT + (size_t)l * N * K;
  #pragma unroll
  for (int i = 0; i < 4; ++i)
    out[(size_t)(n0 + ty + 8 * i) * K + k0 + tx] = f2bf(tile[tx][ty + 8 * i]);
}

// ---------------------------------------------------------------------------
// bf16 MFMA GEMM: C[M,N] = A[M,K] @ BT[N,K]^T (+bias)(+relu)(+resid)
// 128x128 tile, BK=64, 4 waves.  blockIdx.x = M-tile (M fast) for B-panel
// L2/L3 locality; blockIdx.y = N-tile.
// ---------------------------------------------------------------------------
template <bool BIAS, bool RELU, bool RESID, bool OBF16>
__global__ __launch_bounds__(256) void gemm_mfma(
    const u16* __restrict__ A, const u16* __restrict__ BT,
    const float* __restrict__ bias, const float* __restrict__ resid,
    void* __restrict__ Cv, int M, int N, int K) {
  __shared__ u16 As[128 * 64];
  __shared__ u16 Bs[128 * 64];
  const int tid = threadIdx.x;
  const int lane = tid & 63, wave = tid >> 6;
  const int m0 = blockIdx.x * 128, n0 = blockIdx.y * 128;
  const int wr = (wave >> 1) * 64, wc = (wave & 1) * 64;
  const int srow = tid >> 3, scol = (tid & 7) * 8;
  const u16* Ag = A + (size_t)(m0 + srow) * K + scol;
  const u16* Bg = BT + (size_t)(n0 + srow) * K + scol;

  f32x4 acc[4][4] = {};
  for (int k0 = 0; k0 < K; k0 += 64) {
    #pragma unroll
    for (int c = 0; c < 4; ++c) {
      __builtin_amdgcn_global_load_lds(
          (const guint*)(Ag + k0 + (size_t)c * 32 * K),
          (luint*)(As + c * 2048 + tid * 8), 16, 0, 0);
      __builtin_amdgcn_global_load_lds(
          (const guint*)(Bg + k0 + (size_t)c * 32 * K),
          (luint*)(Bs + c * 2048 + tid * 8), 16, 0, 0);
    }
    __syncthreads();
    #pragma unroll
    for (int kk = 0; kk < 64; kk += 32) {
      short8v av[4], bv[4];
      #pragma unroll
      for (int i = 0; i < 4; ++i)
        av[i] = *(const short8v*)(As + (wr + i * 16 + (lane & 15)) * 64 + kk + (lane >> 4) * 8);
      #pragma unroll
      for (int j = 0; j < 4; ++j)
        bv[j] = *(const short8v*)(Bs + (wc + j * 16 + (lane & 15)) * 64 + kk + (lane >> 4) * 8);
      #pragma unroll
      for (int i = 0; i < 4; ++i)
        #pragma unroll
        for (int j = 0; j < 4; ++j)
          acc[i][j] = __builtin_amdgcn_mfma_f32_16x16x32_bf16(av[i], bv[j], acc[i][j], 0, 0, 0);
    }
    __syncthreads();
  }
  #pragma unroll
  for (int i = 0; i < 4; ++i) {
    #pragma unroll
    for (int j = 0; j < 4; ++j) {
      const int col = n0 + wc + j * 16 + (lane & 15);
      #pragma unroll
      for (int r = 0; r < 4; ++r) {
        const int row = m0 + wr + i * 16 + (lane >> 4) * 4 + r;
        float v = acc[i][j][r];
        if (BIAS) v += bias[col];
        if (RELU) v = fmaxf(v, 0.f);
        if (RESID) v += resid[(size_t)row * N + col];
        if (OBF16)
          ((u16*)Cv)[(size_t)row * N + col] = f2bf(v);
        else
          ((float*)Cv)[(size_t)row * N + col] = v;
      }
    }
  }
}

// ---------------------------------------------------------------------------
// Fallback fp32 GEMM for LM head (A bf16, B fp32 [K][N], +bias)
// ---------------------------------------------------------------------------
__global__ __launch_bounds__(256) void gemm_fb(
    const u16* __restrict__ A, const float* __restrict__ B,
    const float* __restrict__ bias, float* __restrict__ C, int M, int N, int K) {
  __shared__ alignas(16) float As[16][68];
  __shared__ alignas(16) float Bs[16][68];
  const int tid = threadIdx.x;
  const int tx = tid & 15, ty = tid >> 4;
  const int m0 = blockIdx.y * 64, n0 = blockIdx.x * 64;
  const int ar = tid >> 2, ac = (tid & 3) * 4;
  const int br = tid >> 4, bc = (tid & 15) * 4;
  float acc[4][4] = {};
  for (int k0 = 0; k0 < K; k0 += 16) {
    ushort4 au = *(const ushort4*)(A + (size_t)(m0 + ar) * K + k0 + ac);
    float4 bv = *(const float4*)(B + (size_t)(k0 + br) * N + n0 + bc);
    As[ac + 0][ar] = bf2f_lo(au.x);
    As[ac + 1][ar] = bf2f_lo(au.y);
    As[ac + 2][ar] = bf2f_lo(au.z);
    As[ac + 3][ar] = bf2f_lo(au.w);
    *(float4*)&Bs[br][bc] = bv;
    __syncthreads();
    #pragma unroll
    for (int kk = 0; kk < 16; ++kk) {
      float4 a = *(const float4*)&As[kk][ty * 4];
      float4 b = *(const float4*)&Bs[kk][tx * 4];
      acc[0][0] += a.x * b.x; acc[0][1] += a.x * b.y; acc[0][2] += a.x * b.z; acc[0][3] += a.x * b.w;
      acc[1][0] += a.y * b.x; acc[1][1] += a.y * b.y; acc[1][2] += a.y * b.z; acc[1][3] += a.y * b.w;
      acc[2][0] += a.z * b.x; acc[2][1] += a.z * b.y; acc[2][2] += a.z * b.z; acc[2][3] += a.z * b.w;
      acc[3][0] += a.w * b.x; acc[3][1] += a.w * b.y; acc[3][2] += a.w * b.z; acc[3][3] += a.w * b.w;
    }
    __syncthreads();
  }
  #pragma unroll
  for (int i = 0; i < 4; ++i) {
    const int m = m0 + ty * 4 + i;
    #pragma unroll
    for (int j = 0; j < 4; ++j) {
      const int n = n0 + tx * 4 + j;
      C[(size_t)m * N + n] = acc[i][j] + bias[n];
    }
  }
}

// ---------------------------------------------------------------------------
// MFMA flash attention.  Block = 256 thr (4 waves), 64 q-rows per block
// (16 per wave), K/V tiles of 64 rows.
// q,k: [b][s][h*64+e] bf16 row-major (stride 1024).
// vt:  [h*64+e][b*S+s] bf16 (stride 4096)  -- produced by transposed V GEMM.
// Swapped QK^T: S^T = mfma(A=K, B=Q); C lane layout: col(lane&15)=q,
// row((lane>>4)*4+reg)=k.  PV: O = mfma(A=P, B=V) with P staged in LDS and
// V^T tiles read as B-fragments.  K/V^T LDS tiles use XOR-(row&7) 16B-chunk
// swizzle, applied on the global source of global_load_lds (LDS dest linear).
// ---------------------------------------------------------------------------
__global__ __launch_bounds__(256) void attn_mfma(
    const u16* __restrict__ q, const u16* __restrict__ k,
    const u16* __restrict__ vt, u16* __restrict__ o) {
  __shared__ alignas(16) u16 Ksh[64 * 64];
  __shared__ alignas(16) u16 Vsh[64 * 64];
  __shared__ unsigned Plds[4][16 * 41];   // per-wave P[q][k] bf16-pairs, 41-dw rows
  __shared__ float bcast[4][16];
  const int tid = threadIdx.x;
  const int lane = tid & 63, wave = tid >> 6;
  const int g = lane >> 4, qi = lane & 15;
  const int qt = blockIdx.x, h = blockIdx.y, b = blockIdx.z;
  const int q0w = qt * 64 + wave * 16;   // wave's first q row (within S)
  const int qloc = wave * 16 + qi;       // this lane's q position within block

  // Q fragments (B-operand rows): 2 chunks of d
  short8v qf0, qf1;
  {
    const u16* qp = q + ((size_t)b * SS + q0w + qi) * DD + h * DHH + g * 8;
    qf0 = *(const short8v*)qp;
    qf1 = *(const short8v*)(qp + 32);
  }

  f32x4 oacc[4] = {};
  float mrow = -1e30f, lrow = 0.f;

  for (int kt = 0; kt <= qt; ++kt) {
    __syncthreads();   // previous tile's LDS reads complete
    // ---- stage K tile [64 k][64 d] and V^T tile [64 dv][64 k], swizzled src
    #pragma unroll
    for (int u = 0; u < 2; ++u) {
      const int unit = tid + 256 * u;
      const int row = unit >> 3, ch = unit & 7;
      const int sch = ch ^ (row & 7);
      __builtin_amdgcn_global_load_lds(
          (const guint*)(k + ((size_t)b * SS + kt * 64 + row) * DD + h * DHH + sch * 8),
          (luint*)(Ksh + unit * 8), 16, 0, 0);
      __builtin_amdgcn_global_load_lds(
          (const guint*)(vt + ((size_t)(h * DHH + row)) * MM + b * SS + kt * 64 + sch * 8),
          (luint*)(Vsh + unit * 8), 16, 0, 0);
    }
    __syncthreads();

    // ---- S^T = K . Q^T   (4 k-subtiles of 16)
    f32x4 st[4] = {};
    #pragma unroll
    for (int t = 0; t < 4; ++t) {
      const int row = t * 16 + qi;
      const int swz = (row & 7) << 4;
      short8v kf0 = *(const short8v*)(Ksh + row * 64 + (((g * 16) ^ swz) >> 1));
      short8v kf1 = *(const short8v*)(Ksh + row * 64 + (((64 + g * 16) ^ swz) >> 1));
      st[t] = __builtin_amdgcn_mfma_f32_16x16x32_bf16(kf0, qf0, st[t], 0, 0, 0);
      st[t] = __builtin_amdgcn_mfma_f32_16x16x32_bf16(kf1, qf1, st[t], 0, 0, 0);
    }

    // ---- causal mask (diagonal tile only): k-index = t*16 + 4g + r
    if (kt == qt) {
      #pragma unroll
      for (int t = 0; t < 4; ++t)
        #pragma unroll
        for (int r = 0; r < 4; ++r)
          if (t * 16 + 4 * g + r > qloc) st[t][r] = -1e30f;
    }

    // ---- online softmax (scale 0.125 folded into exp arg)
    float mt = st[0][0];
    #pragma unroll
    for (int t = 0; t < 4; ++t)
      #pragma unroll
      for (int r = 0; r < 4; ++r) mt = fmaxf(mt, st[t][r]);
    mt = fmaxf(mt, __shfl_xor(mt, 16));
    mt = fmaxf(mt, __shfl_xor(mt, 32));
    const float mnew = fmaxf(mrow, mt * 0.125f);
    const float corr = __expf(mrow - mnew);
    float pl = 0.f;
    #pragma unroll
    for (int t = 0; t < 4; ++t) {
      #pragma unroll
      for (int r2 = 0; r2 < 2; ++r2) {
        float plo = __expf(fmaf(st[t][2 * r2], 0.125f, -mnew));
        float phi = __expf(fmaf(st[t][2 * r2 + 1], 0.125f, -mnew));
        pl += plo + phi;
        Plds[wave][qi * 41 + 8 * t + 2 * g + r2] =
            (unsigned)f2bf(plo) | ((unsigned)f2bf(phi) << 16);
      }
    }
    pl += __shfl_xor(pl, 16);
    pl += __shfl_xor(pl, 32);
    lrow = lrow * corr + pl;
    mrow = mnew;

    // broadcast per-q corr to O-layout lanes (q = 4g + r there)
    if (g == 0) bcast[wave][qi] = corr;
    float c0 = bcast[wave][g * 4 + 0];
    float c1 = bcast[wave][g * 4 + 1];
    float c2 = bcast[wave][g * 4 + 2];
    float c3 = bcast[wave][g * 4 + 3];
    #pragma unroll
    for (int dvt = 0; dvt < 4; ++dvt) {
      oacc[dvt][0] *= c0; oacc[dvt][1] *= c1;
      oacc[dvt][2] *= c2; oacc[dvt][3] *= c3;
    }

    // ---- PV: A-frags of P from LDS, B-frags of V from swizzled V^T tile
    union U8 { unsigned u[4]; short8v s8; };
    U8 pa0, pa1;
    #pragma unroll
    for (int c = 0; c < 4; ++c) {
      pa0.u[c] = Plds[wave][qi * 41 + g * 4 + c];
      pa1.u[c] = Plds[wave][qi * 41 + 16 + g * 4 + c];
    }
    #pragma unroll
    for (int dvt = 0; dvt < 4; ++dvt) {
      const int row = dvt * 16 + qi;
      const int swz = (row & 7) << 4;
      short8v v0 = *(const short8v*)(Vsh + row * 64 + (((g * 16) ^ swz) >> 1));
      short8v v1 = *(const short8v*)(Vsh + row * 64 + (((64 + g * 16) ^ swz) >> 1));
      oacc[dvt] = __builtin_amdgcn_mfma_f32_16x16x32_bf16(pa0.s8, v0, oacc[dvt], 0, 0, 0);
      oacc[dvt] = __builtin_amdgcn_mfma_f32_16x16x32_bf16(pa1.s8, v1, oacc[dvt], 0, 0, 0);
    }
  }

  // ---- normalize + write out
  if (g == 0) bcast[wave][qi] = 1.f / lrow;
  float i0 = bcast[wave][g * 4 + 0];
  float i1 = bcast[wave][g * 4 + 1];
  float i2 = bcast[wave][g * 4 + 2];
  float i3 = bcast[wave][g * 4 + 3];
  #pragma unroll
  for (int dvt = 0; dvt < 4; ++dvt) {
    const int col = h * DHH + dvt * 16 + qi;
    o[((size_t)b * SS + q0w + g * 4 + 0) * DD + col] = f2bf(oacc[dvt][0] * i0);
    o[((size_t)b * SS + q0w + g * 4 + 1) * DD + col] = f2bf(oacc[dvt][1] * i1);
    o[((size_t)b * SS + q0w + g * 4 + 2) * DD + col] = f2bf(oacc[dvt][2] * i2);
    o[((size_t)b * SS + q0w + g * 4 + 3) * DD + col] = f2bf(oacc[dvt][3] * i3);
  }
}

// ---------------------------------------------------------------------------
extern "C" void kernel_launch(void* const* d_in, const int* in_sizes, int n_in,
                              void* d_out, int out_size, void* d_ws, size_t ws_size,
                              hipStream_t stream) {
  const int* idx = (const int*)d_in[0];
  const float* tok_emb = (const float*)d_in[1];
  const float* pos_emb = (const float*)d_in[2];
  const float* ln1_s = (const float*)d_in[3];
  const float* ln1_b = (const float*)d_in[4];
  const float* wq = (const float*)d_in[5];
  const float* wk = (const float*)d_in[6];
  const float* wv = (const float*)d_in[7];
  const float* wproj = (const float*)d_in[8];
  const float* ln2_s = (const float*)d_in[9];
  const float* ln2_b = (const float*)d_in[10];
  const float* w1 = (const float*)d_in[11];
  const float* b1 = (const float*)d_in[12];
  const float* w2 = (const float*)d_in[13];
  const float* b2 = (const float*)d_in[14];
  const float* lnf_s = (const float*)d_in[15];
  const float* lnf_b = (const float*)d_in[16];
  const float* lm_w = (const float*)d_in[17];
  const float* lm_b = (const float*)d_in[18];

  const size_t MD = (size_t)MM * DD;  // 4,194,304

  // d_out scratch (dead before the final LM GEMM writes d_out):
  u16* sc0 = (u16*)d_out;
  u16* BTq = sc0;                                   // 8 x 1M
  u16* BTk = BTq + (size_t)LL * DD * DD;
  u16* BTv = BTk + (size_t)LL * DD * DD;
  u16* BTp = BTv + (size_t)LL * DD * DD;
  u16* BTw1 = BTp + (size_t)LL * DD * DD;           // 8 x 4M
  u16* BTw2 = BTw1 + (size_t)LL * DD * 4 * DD;      // 8 x 4M
  u16* qb = BTw2 + (size_t)LL * DD * 4 * DD;
  u16* kb = qb + MD;
  u16* vtb = kb + MD;                               // V^T [1024][4096]
  u16* ob = vtb + MD;
  u16* tmp = ob + MD;                               // M x 4D

  // d_ws: x fp32 (16MB) + h bf16 (8MB) [+ BT(lm_w) bf16 (65.5MB) if room]
  float* x = (float*)d_ws;
  u16* h = (u16*)((char*)d_ws + MD * 4);
  u16* BTlm = (u16*)((char*)d_ws + MD * 4 + MD * 2);
  const bool big_ws = ws_size >= (MD * 4 + MD * 2 + (size_t)VV * DD * 2);

  const dim3 blk(256);

  convT_kernel<true><<<dim3(DD / 32, DD / 32, LL), blk, 0, stream>>>(wq, BTq, DD, DD);
  convT_kernel<true><<<dim3(DD / 32, DD / 32, LL), blk, 0, stream>>>(wk, BTk, DD, DD);
  convT_kernel<true><<<dim3(DD / 32, DD / 32, LL), blk, 0, stream>>>(wv, BTv, DD, DD);
  convT_kernel<false><<<dim3(DD / 32, DD / 32, LL), blk, 0, stream>>>(wproj, BTp, DD, DD);
  convT_kernel<false><<<dim3(4 * DD / 32, DD / 32, LL), blk, 0, stream>>>(w1, BTw1, DD, 4 * DD);
  convT_kernel<false><<<dim3(DD / 32, 4 * DD / 32, LL), blk, 0, stream>>>(w2, BTw2, 4 * DD, DD);
  if (big_ws)
    convT_kernel<false><<<dim3(VV / 32, DD / 32, 1), blk, 0, stream>>>(lm_w, BTlm, DD, VV);

  embed_kernel<<<(MM * DD / 4 + 255) / 256, blk, 0, stream>>>(idx, tok_emb, pos_emb, x);

  for (int l = 0; l < LL; ++l) {
    ln_bf16_kernel<<<MM, blk, 0, stream>>>(x, ln1_s + l * DD, ln1_b + l * DD, h);
    // Q, K: [s][1024]
    gemm_mfma<false, false, false, true><<<dim3(MM / 128, DD / 128), blk, 0, stream>>>(
        h, BTq + (size_t)l * DD * DD, nullptr, nullptr, qb, MM, DD, DD);
    gemm_mfma<false, false, false, true><<<dim3(MM / 128, DD / 128), blk, 0, stream>>>(
        h, BTk + (size_t)l * DD * DD, nullptr, nullptr, kb, MM, DD, DD);
    // V transposed: C[dv_global][b*S+s] = Wv^T . h^T  (A = BTv, BT = h)
    gemm_mfma<false, false, false, true><<<dim3(DD / 128, MM / 128), blk, 0, stream>>>(
        BTv + (size_t)l * DD * DD, h, nullptr, nullptr, vtb, DD, MM, DD);
    attn_mfma<<<dim3(SS / 64, HH, BB), blk, 0, stream>>>(qb, kb, vtb, ob);
    gemm_mfma<false, false, true, false><<<dim3(MM / 128, DD / 128), blk, 0, stream>>>(
        ob, BTp + (size_t)l * DD * DD, nullptr, x, x, MM, DD, DD);
    ln_bf16_kernel<<<MM, blk, 0, stream>>>(x, ln2_s + l * DD, ln2_b + l * DD, h);
    gemm_mfma<true, true, false, true><<<dim3(MM / 128, 4 * DD / 128), blk, 0, stream>>>(
        h, BTw1 + (size_t)l * DD * 4 * DD, b1 + (size_t)l * 4 * DD, nullptr, tmp,
        MM, 4 * DD, DD);
    gemm_mfma<true, false, true, false><<<dim3(MM / 128, DD / 128), blk, 0, stream>>>(
        tmp, BTw2 + (size_t)l * 4 * DD * DD, b2 + (size_t)l * DD, x, x, MM, DD, 4 * DD);
  }

  ln_bf16_kernel<<<MM, blk, 0, stream>>>(x, lnf_s, lnf_b, h);
  if (big_ws) {
    gemm_mfma<true, false, false, false><<<dim3(MM / 128, VV / 128), blk, 0, stream>>>(
        h, BTlm, lm_b, nullptr, (float*)d_out, MM, VV, DD);
  } else {
    gemm_fb<<<dim3(VV / 64, MM / 64), blk, 0, stream>>>(
        h, lm_w, lm_b, (float*)d_out, MM, VV, DD);
  }
}

// Round 4
// 3000.804 us; speedup vs baseline: 9.7334x; 1.1061x over previous
//
#include <hip/hip_runtime.h>
#include <hip/hip_bf16.h>

// Model dims (fixed by reference)
#define LL 8
#define DD 1024
#define HH 16
#define DHH 64
#define SS 1024
#define BB 4
#define VV 32000
#define MM (BB * SS)   // 4096 rows

typedef unsigned short u16;
typedef __attribute__((ext_vector_type(8))) short short8v;   // 8 bf16 (4 VGPRs)
typedef __attribute__((ext_vector_type(4))) float f32x4;
typedef unsigned int __attribute__((address_space(1))) guint;
typedef unsigned int __attribute__((address_space(3))) luint;

__device__ __forceinline__ float bf2f_lo(unsigned u) { return __uint_as_float(u << 16); }
__device__ __forceinline__ u16 f2bf(float f) {
  unsigned x = __float_as_uint(f);
  return (u16)((x + 0x7fffu + ((x >> 16) & 1u)) >> 16);
}

// ---------------------------------------------------------------------------
// Embedding
// ---------------------------------------------------------------------------
__global__ __launch_bounds__(256) void embed_kernel(
    const int* __restrict__ idx, const float* __restrict__ tok,
    const float* __restrict__ pos, float* __restrict__ x) {
  int i = blockIdx.x * blockDim.x + threadIdx.x;
  int elem = i * 4;
  int row = elem / DD;
  int d = elem % DD;
  int s = row % SS;
  int t = idx[row];
  float4 tv = *(const float4*)(tok + (size_t)t * DD + d);
  float4 pv = *(const float4*)(pos + (size_t)s * DD + d);
  tv.x += pv.x; tv.y += pv.y; tv.z += pv.z; tv.w += pv.w;
  *(float4*)(x + (size_t)elem) = tv;
}

// ---------------------------------------------------------------------------
// LayerNorm over D=1024 (fp32 in, bf16 out)
// ---------------------------------------------------------------------------
__global__ __launch_bounds__(256) void ln_bf16_kernel(
    const float* __restrict__ x, const float* __restrict__ sc,
    const float* __restrict__ bi, u16* __restrict__ out) {
  const int row = blockIdx.x;
  const int tid = threadIdx.x;
  __shared__ float red[4];
  float4 v = ((const float4*)(x + (size_t)row * DD))[tid];
  float s = v.x + v.y + v.z + v.w;
  #pragma unroll
  for (int off = 32; off; off >>= 1) s += __shfl_down(s, off);
  if ((tid & 63) == 0) red[tid >> 6] = s;
  __syncthreads();
  float mean = (red[0] + red[1] + red[2] + red[3]) * (1.f / DD);
  float dx = v.x - mean, dy = v.y - mean, dz = v.z - mean, dw = v.w - mean;
  float vs = dx * dx + dy * dy + dz * dz + dw * dw;
  __syncthreads();
  #pragma unroll
  for (int off = 32; off; off >>= 1) vs += __shfl_down(vs, off);
  if ((tid & 63) == 0) red[tid >> 6] = vs;
  __syncthreads();
  float var = (red[0] + red[1] + red[2] + red[3]) * (1.f / DD);
  float rstd = rsqrtf(var + 1e-5f);
  float4 s4 = ((const float4*)sc)[tid];
  float4 b4 = ((const float4*)bi)[tid];
  ushort4 o;
  o.x = f2bf(dx * rstd * s4.x + b4.x);
  o.y = f2bf(dy * rstd * s4.y + b4.y);
  o.z = f2bf(dz * rstd * s4.z + b4.z);
  o.w = f2bf(dw * rstd * s4.w + b4.w);
  *(ushort4*)(out + (size_t)row * DD + tid * 4) = o;
}

// ---------------------------------------------------------------------------
// Weight transpose + fp32->bf16: W [l][K][N] (or head-blocked) -> BT rows [N][K]
// at BT + l*lstride.
// ---------------------------------------------------------------------------
template <bool HEADW>
__global__ __launch_bounds__(256) void convT_kernel(
    const float* __restrict__ W, u16* __restrict__ BT, int K, int N,
    size_t lstride) {
  __shared__ float tile[32][33];
  const int n0 = blockIdx.x * 32, k0 = blockIdx.y * 32, l = blockIdx.z;
  const int tx = threadIdx.x & 31, ty = threadIdx.x >> 5;
  const float* Wl;
  int ld;
  if (HEADW) {
    const int h = n0 >> 6;
    Wl = W + ((size_t)(l * HH + h) * K) * 64 + (n0 & 63);
    ld = 64;
  } else {
    Wl = W + (size_t)l * K * N + n0;
    ld = N;
  }
  #pragma unroll
  for (int i = 0; i < 4; ++i)
    tile[ty + 8 * i][tx] = Wl[(size_t)(k0 + ty + 8 * i) * ld + tx];
  __syncthreads();
  u16* out = BT + (size_t)l * lstride;
  #pragma unroll
  for (int i = 0; i < 4; ++i)
    out[(size_t)(n0 + ty + 8 * i) * K + k0 + tx] = f2bf(tile[tx][ty + 8 * i]);
}

// ---------------------------------------------------------------------------
// bf16 MFMA GEMM (m97 structure): 128x128 tile, BK=64, 4 waves.
// Used for the small-N per-layer GEMMs (vt / proj / MLP2).
// ---------------------------------------------------------------------------
template <bool BIAS, bool RELU, bool RESID, bool OBF16>
__global__ __launch_bounds__(256) void gemm_mfma(
    const u16* __restrict__ A, const u16* __restrict__ BT,
    const float* __restrict__ bias, const float* __restrict__ resid,
    void* __restrict__ Cv, int M, int N, int K) {
  __shared__ u16 As[128 * 64];
  __shared__ u16 Bs[128 * 64];
  const int tid = threadIdx.x;
  const int lane = tid & 63, wave = tid >> 6;
  const int m0 = blockIdx.x * 128, n0 = blockIdx.y * 128;
  const int wr = (wave >> 1) * 64, wc = (wave & 1) * 64;
  const int srow = tid >> 3, scol = (tid & 7) * 8;
  const u16* Ag = A + (size_t)(m0 + srow) * K + scol;
  const u16* Bg = BT + (size_t)(n0 + srow) * K + scol;

  f32x4 acc[4][4] = {};
  for (int k0 = 0; k0 < K; k0 += 64) {
    #pragma unroll
    for (int c = 0; c < 4; ++c) {
      __builtin_amdgcn_global_load_lds(
          (const guint*)(Ag + k0 + (size_t)c * 32 * K),
          (luint*)(As + c * 2048 + tid * 8), 16, 0, 0);
      __builtin_amdgcn_global_load_lds(
          (const guint*)(Bg + k0 + (size_t)c * 32 * K),
          (luint*)(Bs + c * 2048 + tid * 8), 16, 0, 0);
    }
    __syncthreads();
    #pragma unroll
    for (int kk = 0; kk < 64; kk += 32) {
      short8v av[4], bv[4];
      #pragma unroll
      for (int i = 0; i < 4; ++i)
        av[i] = *(const short8v*)(As + (wr + i * 16 + (lane & 15)) * 64 + kk + (lane >> 4) * 8);
      #pragma unroll
      for (int j = 0; j < 4; ++j)
        bv[j] = *(const short8v*)(Bs + (wc + j * 16 + (lane & 15)) * 64 + kk + (lane >> 4) * 8);
      #pragma unroll
      for (int i = 0; i < 4; ++i)
        #pragma unroll
        for (int j = 0; j < 4; ++j)
          acc[i][j] = __builtin_amdgcn_mfma_f32_16x16x32_bf16(av[i], bv[j], acc[i][j], 0, 0, 0);
    }
    __syncthreads();
  }
  #pragma unroll
  for (int i = 0; i < 4; ++i) {
    #pragma unroll
    for (int j = 0; j < 4; ++j) {
      const int col = n0 + wc + j * 16 + (lane & 15);
      #pragma unroll
      for (int r = 0; r < 4; ++r) {
        const int row = m0 + wr + i * 16 + (lane >> 4) * 4 + r;
        float v = acc[i][j][r];
        if (BIAS) v += bias[col];
        if (RELU) v = fmaxf(v, 0.f);
        if (RESID) v += resid[(size_t)row * N + col];
        if (OBF16)
          ((u16*)Cv)[(size_t)row * N + col] = f2bf(v);
        else
          ((float*)Cv)[(size_t)row * N + col] = v;
      }
    }
  }
}

// ---------------------------------------------------------------------------
// 8-phase 256x256 GEMM (T2-layout + T3/T4 counted-vmcnt + T5 setprio).
// C[M,N] = A[M,K] @ BT[N,K]^T (+bias)(+relu)(+resid), bf16 in, fp32/bf16 out.
// 512 thr = 8 waves (2M x 4N); per-wave C = 128x64 (8 m-frags x 4 n-frags).
// LDS: per operand [2 buf][2 k-half] regions of 256r x 32c bf16 (16 KiB).
// 64B row stride -> frag ds_read_b128 is bank-uniform (no swizzle needed).
// Per K-tile: 4 phases; stages issued 5-6 phases before use; vmcnt(8) twice
// per tile (drains 8->4->0 only in the last two peeled tiles).
// ---------------------------------------------------------------------------
#define LDA_(BUF, KH, F) \
  (*(const short8v*)&As[BUF][KH][(wm * 128 + (F) * 16 + (lane & 15)) * 32 + (lane >> 4) * 8])
#define LDB_(BUF, KH, NF) \
  (*(const short8v*)&Bs[BUF][KH][(wn * 64 + (NF) * 16 + (lane & 15)) * 32 + (lane >> 4) * 8])
#define PH_A(BUF, KH, FB) { a0 = LDA_(BUF, KH, (FB) + 0); a1 = LDA_(BUF, KH, (FB) + 1); \
                            a2 = LDA_(BUF, KH, (FB) + 2); a3 = LDA_(BUF, KH, (FB) + 3); }
#define PH_B(BUF, KH)     { b0 = LDB_(BUF, KH, 0); b1 = LDB_(BUF, KH, 1); \
                            b2 = LDB_(BUF, KH, 2); b3 = LDB_(BUF, KH, 3); }
#define STAGE_A(BUF, KH, KT) do { \
  __builtin_amdgcn_global_load_lds((const guint*)(Abase + (KT) * 64 + (KH) * 32), \
      (luint*)(&As[BUF][KH][tid * 8]), 16, 0, 0); \
  __builtin_amdgcn_global_load_lds((const guint*)(Abase + (size_t)128 * K + (KT) * 64 + (KH) * 32), \
      (luint*)(&As[BUF][KH][(tid + 512) * 8]), 16, 0, 0); \
} while (0)
#define STAGE_B(BUF, KH, KT) do { \
  __builtin_amdgcn_global_load_lds((const guint*)(Bbase + (KT) * 64 + (KH) * 32), \
      (luint*)(&Bs[BUF][KH][tid * 8]), 16, 0, 0); \
  __builtin_amdgcn_global_load_lds((const guint*)(Bbase + (size_t)128 * K + (KT) * 64 + (KH) * 32), \
      (luint*)(&Bs[BUF][KH][(tid + 512) * 8]), 16, 0, 0); \
} while (0)
#define MFMA_ROW(F, AQ) \
  acc[F][0] = __builtin_amdgcn_mfma_f32_16x16x32_bf16(AQ, b0, acc[F][0], 0, 0, 0); \
  acc[F][1] = __builtin_amdgcn_mfma_f32_16x16x32_bf16(AQ, b1, acc[F][1], 0, 0, 0); \
  acc[F][2] = __builtin_amdgcn_mfma_f32_16x16x32_bf16(AQ, b2, acc[F][2], 0, 0, 0); \
  acc[F][3] = __builtin_amdgcn_mfma_f32_16x16x32_bf16(AQ, b3, acc[F][3], 0, 0, 0);
#define MFMA16(FB) MFMA_ROW((FB) + 0, a0) MFMA_ROW((FB) + 1, a1) \
                   MFMA_ROW((FB) + 2, a2) MFMA_ROW((FB) + 3, a3)
#define BARRIER __builtin_amdgcn_s_barrier()
#define LGKM0 asm volatile("s_waitcnt lgkmcnt(0)" ::: "memory")
#define MEMFENCE asm volatile("" ::: "memory")

#define TILE8(CUR, KT, ST1, ST2, V1STR, DOV3, V3STR) { \
  const int cur_ = (CUR); \
  MEMFENCE; \
  PH_B(cur_, 0); PH_A(cur_, 0, 0); \
  if (ST1) { STAGE_A(cur_ ^ 1, 1, (KT) + 1); } \
  BARRIER; LGKM0; \
  __builtin_amdgcn_s_setprio(1); MFMA16(0); __builtin_amdgcn_s_setprio(0); \
  BARRIER; MEMFENCE; \
  PH_A(cur_, 0, 4); \
  if (ST1) { STAGE_B(cur_ ^ 1, 1, (KT) + 1); } \
  asm volatile("s_waitcnt " V1STR ::: "memory"); \
  BARRIER; LGKM0; \
  __builtin_amdgcn_s_setprio(1); MFMA16(4); __builtin_amdgcn_s_setprio(0); \
  BARRIER; MEMFENCE; \
  PH_B(cur_, 1); PH_A(cur_, 1, 0); \
  if (ST2) { STAGE_A(cur_, 0, (KT) + 2); } \
  BARRIER; LGKM0; \
  __builtin_amdgcn_s_setprio(1); MFMA16(0); __builtin_amdgcn_s_setprio(0); \
  BARRIER; MEMFENCE; \
  PH_A(cur_, 1, 4); \
  if (ST2) { STAGE_B(cur_, 0, (KT) + 2); } \
  if (DOV3) { asm volatile("s_waitcnt " V3STR ::: "memory"); } \
  BARRIER; LGKM0; \
  __builtin_amdgcn_s_setprio(1); MFMA16(4); __builtin_amdgcn_s_setprio(0); \
  BARRIER; \
}

template <bool BIAS, bool RELU, bool RESID, bool OBF16>
__global__ __launch_bounds__(512, 2) void gemm8(
    const u16* __restrict__ A, const u16* __restrict__ BT,
    const float* __restrict__ bias, const float* __restrict__ resid,
    void* __restrict__ Cv, int M, int N, int K) {
  __shared__ u16 As[2][2][8192];
  __shared__ u16 Bs[2][2][8192];
  const int tid = threadIdx.x;
  const int lane = tid & 63, wave = tid >> 6;
  const int wm = wave >> 2, wn = wave & 3;
  const int nwg = gridDim.x;
  const int bid = blockIdx.x;
  const int wg = ((nwg & 7) == 0) ? ((bid & 7) * (nwg >> 3) + (bid >> 3)) : bid;
  const int nmt = M >> 8;
  const int m0 = (wg % nmt) * 256;
  const int n0 = (wg / nmt) * 256;
  const int NT = K >> 6;
  const int sr = tid >> 2;       // staging row (+0 / +128)
  const int sc = tid & 3;        // staging 16B chunk
  const u16* Abase = A + (size_t)(m0 + sr) * K + sc * 8;
  const u16* Bbase = BT + (size_t)(n0 + sr) * K + sc * 8;

  f32x4 acc[8][4] = {};
  short8v a0, a1, a2, a3, b0, b1, b2, b3;

  // Prologue: tile0 (both k-halves) + tile1 k0; validate tile0 k0.
  STAGE_A(0, 0, 0); STAGE_B(0, 0, 0);
  STAGE_A(0, 1, 0); STAGE_B(0, 1, 0);
  STAGE_A(1, 0, 1); STAGE_B(1, 0, 1);
  asm volatile("s_waitcnt vmcnt(8)" ::: "memory");
  BARRIER;

  int kt = 0;
  for (; kt < NT - 2; ++kt) {
    TILE8(kt & 1, kt, true, true, "vmcnt(8)", true, "vmcnt(8)");
  }
  TILE8(kt & 1, kt, true, false, "vmcnt(8)", true, "vmcnt(4)");
  ++kt;
  TILE8(kt & 1, kt, false, false, "vmcnt(0)", false, "vmcnt(0)");

  // Epilogue
  #pragma unroll
  for (int f = 0; f < 8; ++f) {
    #pragma unroll
    for (int n = 0; n < 4; ++n) {
      const int col = n0 + wn * 64 + n * 16 + (lane & 15);
      #pragma unroll
      for (int r = 0; r < 4; ++r) {
        const int row = m0 + wm * 128 + f * 16 + (lane >> 4) * 4 + r;
        float v = acc[f][n][r];
        if (BIAS) v += bias[col];
        if (RELU) v = fmaxf(v, 0.f);
        if (RESID) v += resid[(size_t)row * N + col];
        if (OBF16)
          ((u16*)Cv)[(size_t)row * N + col] = f2bf(v);
        else
          ((float*)Cv)[(size_t)row * N + col] = v;
      }
    }
  }
}

// ---------------------------------------------------------------------------
// Fallback fp32 GEMM for LM head (A bf16, B fp32 [K][N], +bias)
// ---------------------------------------------------------------------------
__global__ __launch_bounds__(256) void gemm_fb(
    const u16* __restrict__ A, const float* __restrict__ B,
    const float* __restrict__ bias, float* __restrict__ C, int M, int N, int K) {
  __shared__ alignas(16) float Asm[16][68];
  __shared__ alignas(16) float Bsm[16][68];
  const int tid = threadIdx.x;
  const int tx = tid & 15, ty = tid >> 4;
  const int m0 = blockIdx.y * 64, n0 = blockIdx.x * 64;
  const int ar = tid >> 2, ac = (tid & 3) * 4;
  const int br = tid >> 4, bc = (tid & 15) * 4;
  float acc[4][4] = {};
  for (int k0 = 0; k0 < K; k0 += 16) {
    ushort4 au = *(const ushort4*)(A + (size_t)(m0 + ar) * K + k0 + ac);
    float4 bv = *(const float4*)(B + (size_t)(k0 + br) * N + n0 + bc);
    Asm[ac + 0][ar] = bf2f_lo(au.x);
    Asm[ac + 1][ar] = bf2f_lo(au.y);
    Asm[ac + 2][ar] = bf2f_lo(au.z);
    Asm[ac + 3][ar] = bf2f_lo(au.w);
    *(float4*)&Bsm[br][bc] = bv;
    __syncthreads();
    #pragma unroll
    for (int kk = 0; kk < 16; ++kk) {
      float4 a = *(const float4*)&Asm[kk][ty * 4];
      float4 b = *(const float4*)&Bsm[kk][tx * 4];
      acc[0][0] += a.x * b.x; acc[0][1] += a.x * b.y; acc[0][2] += a.x * b.z; acc[0][3] += a.x * b.w;
      acc[1][0] += a.y * b.x; acc[1][1] += a.y * b.y; acc[1][2] += a.y * b.z; acc[1][3] += a.y * b.w;
      acc[2][0] += a.z * b.x; acc[2][1] += a.z * b.y; acc[2][2] += a.z * b.z; acc[2][3] += a.z * b.w;
      acc[3][0] += a.w * b.x; acc[3][1] += a.w * b.y; acc[3][2] += a.w * b.z; acc[3][3] += a.w * b.w;
    }
    __syncthreads();
  }
  #pragma unroll
  for (int i = 0; i < 4; ++i) {
    const int m = m0 + ty * 4 + i;
    #pragma unroll
    for (int j = 0; j < 4; ++j) {
      const int n = n0 + tx * 4 + j;
      C[(size_t)m * N + n] = acc[i][j] + bias[n];
    }
  }
}

// ---------------------------------------------------------------------------
// MFMA flash attention (as round 3, passing) — q/k now interleaved in qkb:
// qk[b*S+s][0..1023]=Q heads, [1024..2047]=K heads (row stride 2048).
// vt: [h*64+e][b*S+s] bf16 (stride MM).
// ---------------------------------------------------------------------------
__global__ __launch_bounds__(256) void attn_mfma(
    const u16* __restrict__ qk, const u16* __restrict__ vt,
    u16* __restrict__ o) {
  __shared__ alignas(16) u16 Ksh[64 * 64];
  __shared__ alignas(16) u16 Vsh[64 * 64];
  __shared__ unsigned Plds[4][16 * 41];
  __shared__ float bcast[4][16];
  const int tid = threadIdx.x;
  const int lane = tid & 63, wave = tid >> 6;
  const int g = lane >> 4, qi = lane & 15;
  const int qt = blockIdx.x, h = blockIdx.y, b = blockIdx.z;
  const int q0w = qt * 64 + wave * 16;
  const int qloc = wave * 16 + qi;

  short8v qf0, qf1;
  {
    const u16* qp = qk + ((size_t)b * SS + q0w + qi) * 2048 + h * DHH + g * 8;
    qf0 = *(const short8v*)qp;
    qf1 = *(const short8v*)(qp + 32);
  }

  f32x4 oacc[4] = {};
  float mrow = -1e30f, lrow = 0.f;

  for (int kt = 0; kt <= qt; ++kt) {
    __syncthreads();
    #pragma unroll
    for (int u = 0; u < 2; ++u) {
      const int unit = tid + 256 * u;
      const int row = unit >> 3, ch = unit & 7;
      const int sch = ch ^ (row & 7);
      __builtin_amdgcn_global_load_lds(
          (const guint*)(qk + ((size_t)b * SS + kt * 64 + row) * 2048 + 1024 + h * DHH + sch * 8),
          (luint*)(Ksh + unit * 8), 16, 0, 0);
      __builtin_amdgcn_global_load_lds(
          (const guint*)(vt + ((size_t)(h * DHH + row)) * MM + b * SS + kt * 64 + sch * 8),
          (luint*)(Vsh + unit * 8), 16, 0, 0);
    }
    __syncthreads();

    f32x4 st[4] = {};
    #pragma unroll
    for (int t = 0; t < 4; ++t) {
      const int row = t * 16 + qi;
      const int swz = (row & 7) << 4;
      short8v kf0 = *(const short8v*)(Ksh + row * 64 + (((g * 16) ^ swz) >> 1));
      short8v kf1 = *(const short8v*)(Ksh + row * 64 + (((64 + g * 16) ^ swz) >> 1));
      st[t] = __builtin_amdgcn_mfma_f32_16x16x32_bf16(kf0, qf0, st[t], 0, 0, 0);
      st[t] = __builtin_amdgcn_mfma_f32_16x16x32_bf16(kf1, qf1, st[t], 0, 0, 0);
    }

    if (kt == qt) {
      #pragma unroll
      for (int t = 0; t < 4; ++t)
        #pragma unroll
        for (int r = 0; r < 4; ++r)
          if (t * 16 + 4 * g + r > qloc) st[t][r] = -1e30f;
    }

    float mt = st[0][0];
    #pragma unroll
    for (int t = 0; t < 4; ++t)
      #pragma unroll
      for (int r = 0; r < 4; ++r) mt = fmaxf(mt, st[t][r]);
    mt = fmaxf(mt, __shfl_xor(mt, 16));
    mt = fmaxf(mt, __shfl_xor(mt, 32));
    const float mnew = fmaxf(mrow, mt * 0.125f);
    const float corr = __expf(mrow - mnew);
    float pl = 0.f;
    #pragma unroll
    for (int t = 0; t < 4; ++t) {
      #pragma unroll
      for (int r2 = 0; r2 < 2; ++r2) {
        float plo = __expf(fmaf(st[t][2 * r2], 0.125f, -mnew));
        float phi = __expf(fmaf(st[t][2 * r2 + 1], 0.125f, -mnew));
        pl += plo + phi;
        Plds[wave][qi * 41 + 8 * t + 2 * g + r2] =
            (unsigned)f2bf(plo) | ((unsigned)f2bf(phi) << 16);
      }
    }
    pl += __shfl_xor(pl, 16);
    pl += __shfl_xor(pl, 32);
    lrow = lrow * corr + pl;
    mrow = mnew;

    if (g == 0) bcast[wave][qi] = corr;
    float c0 = bcast[wave][g * 4 + 0];
    float c1 = bcast[wave][g * 4 + 1];
    float c2 = bcast[wave][g * 4 + 2];
    float c3 = bcast[wave][g * 4 + 3];
    #pragma unroll
    for (int dvt = 0; dvt < 4; ++dvt) {
      oacc[dvt][0] *= c0; oacc[dvt][1] *= c1;
      oacc[dvt][2] *= c2; oacc[dvt][3] *= c3;
    }

    union U8 { unsigned u[4]; short8v s8; };
    U8 pa0, pa1;
    #pragma unroll
    for (int c = 0; c < 4; ++c) {
      pa0.u[c] = Plds[wave][qi * 41 + g * 4 + c];
      pa1.u[c] = Plds[wave][qi * 41 + 16 + g * 4 + c];
    }
    #pragma unroll
    for (int dvt = 0; dvt < 4; ++dvt) {
      const int row = dvt * 16 + qi;
      const int swz = (row & 7) << 4;
      short8v v0 = *(const short8v*)(Vsh + row * 64 + (((g * 16) ^ swz) >> 1));
      short8v v1 = *(const short8v*)(Vsh + row * 64 + (((64 + g * 16) ^ swz) >> 1));
      oacc[dvt] = __builtin_amdgcn_mfma_f32_16x16x32_bf16(pa0.s8, v0, oacc[dvt], 0, 0, 0);
      oacc[dvt] = __builtin_amdgcn_mfma_f32_16x16x32_bf16(pa1.s8, v1, oacc[dvt], 0, 0, 0);
    }
  }

  if (g == 0) bcast[wave][qi] = 1.f / lrow;
  float i0 = bcast[wave][g * 4 + 0];
  float i1 = bcast[wave][g * 4 + 1];
  float i2 = bcast[wave][g * 4 + 2];
  float i3 = bcast[wave][g * 4 + 3];
  #pragma unroll
  for (int dvt = 0; dvt < 4; ++dvt) {
    const int col = h * DHH + dvt * 16 + qi;
    o[((size_t)b * SS + q0w + g * 4 + 0) * DD + col] = f2bf(oacc[dvt][0] * i0);
    o[((size_t)b * SS + q0w + g * 4 + 1) * DD + col] = f2bf(oacc[dvt][1] * i1);
    o[((size_t)b * SS + q0w + g * 4 + 2) * DD + col] = f2bf(oacc[dvt][2] * i2);
    o[((size_t)b * SS + q0w + g * 4 + 3) * DD + col] = f2bf(oacc[dvt][3] * i3);
  }
}

// ---------------------------------------------------------------------------
extern "C" void kernel_launch(void* const* d_in, const int* in_sizes, int n_in,
                              void* d_out, int out_size, void* d_ws, size_t ws_size,
                              hipStream_t stream) {
  const int* idx = (const int*)d_in[0];
  const float* tok_emb = (const float*)d_in[1];
  const float* pos_emb = (const float*)d_in[2];
  const float* ln1_s = (const float*)d_in[3];
  const float* ln1_b = (const float*)d_in[4];
  const float* wq = (const float*)d_in[5];
  const float* wk = (const float*)d_in[6];
  const float* wv = (const float*)d_in[7];
  const float* wproj = (const float*)d_in[8];
  const float* ln2_s = (const float*)d_in[9];
  const float* ln2_b = (const float*)d_in[10];
  const float* w1 = (const float*)d_in[11];
  const float* b1 = (const float*)d_in[12];
  const float* w2 = (const float*)d_in[13];
  const float* b2 = (const float*)d_in[14];
  const float* lnf_s = (const float*)d_in[15];
  const float* lnf_b = (const float*)d_in[16];
  const float* lm_w = (const float*)d_in[17];
  const float* lm_b = (const float*)d_in[18];

  const size_t MD = (size_t)MM * DD;

  // d_out scratch (268 MB of 524 MB; all dead before the LM GEMM writes d_out)
  u16* sc0 = (u16*)d_out;
  u16* BTqk = sc0;                                   // LL x [2048][1024] (q rows 0-1023, k rows 1024-2047)
  u16* BTv = BTqk + (size_t)LL * 2048 * DD;
  u16* BTp = BTv + (size_t)LL * DD * DD;
  u16* BTw1 = BTp + (size_t)LL * DD * DD;
  u16* BTw2 = BTw1 + (size_t)LL * DD * 4 * DD;
  u16* qkb = BTw2 + (size_t)LL * DD * 4 * DD;        // [M][2048]
  u16* vtb = qkb + (size_t)MM * 2048;                // [1024][4096]
  u16* ob = vtb + MD;
  u16* tmp = ob + MD;                                // [M][4096]

  // d_ws: x fp32 (16MB) + h bf16 (8MB) + BT(lm_w) bf16 (65.5MB) if room
  float* x = (float*)d_ws;
  u16* h = (u16*)((char*)d_ws + MD * 4);
  u16* BTlm = (u16*)((char*)d_ws + MD * 4 + MD * 2);
  const bool big_ws = ws_size >= (MD * 4 + MD * 2 + (size_t)VV * DD * 2);

  const dim3 blk(256);

  convT_kernel<true><<<dim3(DD / 32, DD / 32, LL), blk, 0, stream>>>(
      wq, BTqk, DD, DD, (size_t)2048 * DD);
  convT_kernel<true><<<dim3(DD / 32, DD / 32, LL), blk, 0, stream>>>(
      wk, BTqk + (size_t)DD * DD, DD, DD, (size_t)2048 * DD);
  convT_kernel<true><<<dim3(DD / 32, DD / 32, LL), blk, 0, stream>>>(
      wv, BTv, DD, DD, (size_t)DD * DD);
  convT_kernel<false><<<dim3(DD / 32, DD / 32, LL), blk, 0, stream>>>(
      wproj, BTp, DD, DD, (size_t)DD * DD);
  convT_kernel<false><<<dim3(4 * DD / 32, DD / 32, LL), blk, 0, stream>>>(
      w1, BTw1, DD, 4 * DD, (size_t)DD * 4 * DD);
  convT_kernel<false><<<dim3(DD / 32, 4 * DD / 32, LL), blk, 0, stream>>>(
      w2, BTw2, 4 * DD, DD, (size_t)4 * DD * DD);
  if (big_ws)
    convT_kernel<false><<<dim3(VV / 32, DD / 32, 1), blk, 0, stream>>>(
        lm_w, BTlm, DD, VV, (size_t)VV * DD);

  embed_kernel<<<(MM * DD / 4 + 255) / 256, blk, 0, stream>>>(idx, tok_emb, pos_emb, x);

  for (int l = 0; l < LL; ++l) {
    ln_bf16_kernel<<<MM, blk, 0, stream>>>(x, ln1_s + l * DD, ln1_b + l * DD, h);
    // Fused Q+K (8-phase): C = h @ [Wq|Wk], N=2048
    gemm8<false, false, false, true><<<dim3((MM / 256) * (2048 / 256)), dim3(512), 0, stream>>>(
        h, BTqk + (size_t)l * 2048 * DD, nullptr, nullptr, qkb, MM, 2048, DD);
    // V transposed: C[dv][s] = Wv^T . h^T
    gemm_mfma<false, false, false, true><<<dim3(DD / 128, MM / 128), blk, 0, stream>>>(
        BTv + (size_t)l * DD * DD, h, nullptr, nullptr, vtb, DD, MM, DD);
    attn_mfma<<<dim3(SS / 64, HH, BB), blk, 0, stream>>>(qkb, vtb, ob);
    gemm_mfma<false, false, true, false><<<dim3(MM / 128, DD / 128), blk, 0, stream>>>(
        ob, BTp + (size_t)l * DD * DD, nullptr, x, x, MM, DD, DD);
    ln_bf16_kernel<<<MM, blk, 0, stream>>>(x, ln2_s + l * DD, ln2_b + l * DD, h);
    // MLP1 (8-phase)
    gemm8<true, true, false, true><<<dim3((MM / 256) * (4 * DD / 256)), dim3(512), 0, stream>>>(
        h, BTw1 + (size_t)l * DD * 4 * DD, b1 + (size_t)l * 4 * DD, nullptr, tmp,
        MM, 4 * DD, DD);
    gemm_mfma<true, false, true, false><<<dim3(MM / 128, DD / 128), blk, 0, stream>>>(
        tmp, BTw2 + (size_t)l * 4 * DD * DD, b2 + (size_t)l * DD, x, x, MM, DD, 4 * DD);
  }

  ln_bf16_kernel<<<MM, blk, 0, stream>>>(x, lnf_s, lnf_b, h);
  if (big_ws) {
    gemm8<true, false, false, false><<<dim3((MM / 256) * (VV / 256)), dim3(512), 0, stream>>>(
        h, BTlm, lm_b, nullptr, (float*)d_out, MM, VV, DD);
  } else {
    gemm_fb<<<dim3(VV / 64, MM / 64), blk, 0, stream>>>(
        h, lm_w, lm_b, (float*)d_out, MM, VV, DD);
  }
}

// Round 5
// 2887.851 us; speedup vs baseline: 10.1141x; 1.0391x over previous
//
#include <hip/hip_runtime.h>
#include <hip/hip_bf16.h>

// Model dims (fixed by reference)
#define LL 8
#define DD 1024
#define HH 16
#define DHH 64
#define SS 1024
#define BB 4
#define VV 32000
#define MM (BB * SS)   // 4096 rows

typedef unsigned short u16;
typedef __attribute__((ext_vector_type(8))) short short8v;   // 8 bf16 (4 VGPRs)
typedef __attribute__((ext_vector_type(4))) float f32x4;
typedef unsigned int __attribute__((address_space(1))) guint;
typedef unsigned int __attribute__((address_space(3))) luint;

__device__ __forceinline__ float bf2f_lo(unsigned u) { return __uint_as_float(u << 16); }
__device__ __forceinline__ u16 f2bf(float f) {
  unsigned x = __float_as_uint(f);
  return (u16)((x + 0x7fffu + ((x >> 16) & 1u)) >> 16);
}

// ---------------------------------------------------------------------------
// Embedding
// ---------------------------------------------------------------------------
__global__ __launch_bounds__(256) void embed_kernel(
    const int* __restrict__ idx, const float* __restrict__ tok,
    const float* __restrict__ pos, float* __restrict__ x) {
  int i = blockIdx.x * blockDim.x + threadIdx.x;
  int elem = i * 4;
  int row = elem / DD;
  int d = elem % DD;
  int s = row % SS;
  int t = idx[row];
  float4 tv = *(const float4*)(tok + (size_t)t * DD + d);
  float4 pv = *(const float4*)(pos + (size_t)s * DD + d);
  tv.x += pv.x; tv.y += pv.y; tv.z += pv.z; tv.w += pv.w;
  *(float4*)(x + (size_t)elem) = tv;
}

// ---------------------------------------------------------------------------
// LayerNorm over D=1024 (fp32 in, bf16 out)
// ---------------------------------------------------------------------------
__global__ __launch_bounds__(256) void ln_bf16_kernel(
    const float* __restrict__ x, const float* __restrict__ sc,
    const float* __restrict__ bi, u16* __restrict__ out) {
  const int row = blockIdx.x;
  const int tid = threadIdx.x;
  __shared__ float red[4];
  float4 v = ((const float4*)(x + (size_t)row * DD))[tid];
  float s = v.x + v.y + v.z + v.w;
  #pragma unroll
  for (int off = 32; off; off >>= 1) s += __shfl_down(s, off);
  if ((tid & 63) == 0) red[tid >> 6] = s;
  __syncthreads();
  float mean = (red[0] + red[1] + red[2] + red[3]) * (1.f / DD);
  float dx = v.x - mean, dy = v.y - mean, dz = v.z - mean, dw = v.w - mean;
  float vs = dx * dx + dy * dy + dz * dz + dw * dw;
  __syncthreads();
  #pragma unroll
  for (int off = 32; off; off >>= 1) vs += __shfl_down(vs, off);
  if ((tid & 63) == 0) red[tid >> 6] = vs;
  __syncthreads();
  float var = (red[0] + red[1] + red[2] + red[3]) * (1.f / DD);
  float rstd = rsqrtf(var + 1e-5f);
  float4 s4 = ((const float4*)sc)[tid];
  float4 b4 = ((const float4*)bi)[tid];
  ushort4 o;
  o.x = f2bf(dx * rstd * s4.x + b4.x);
  o.y = f2bf(dy * rstd * s4.y + b4.y);
  o.z = f2bf(dz * rstd * s4.z + b4.z);
  o.w = f2bf(dw * rstd * s4.w + b4.w);
  *(ushort4*)(out + (size_t)row * DD + tid * 4) = o;
}

// ---------------------------------------------------------------------------
// Weight transpose + fp32->bf16: W [l][K][N] (or head-blocked) -> BT rows [N][K]
// at BT + l*lstride.
// ---------------------------------------------------------------------------
template <bool HEADW>
__global__ __launch_bounds__(256) void convT_kernel(
    const float* __restrict__ W, u16* __restrict__ BT, int K, int N,
    size_t lstride) {
  __shared__ float tile[32][33];
  const int n0 = blockIdx.x * 32, k0 = blockIdx.y * 32, l = blockIdx.z;
  const int tx = threadIdx.x & 31, ty = threadIdx.x >> 5;
  const float* Wl;
  int ld;
  if (HEADW) {
    const int h = n0 >> 6;
    Wl = W + ((size_t)(l * HH + h) * K) * 64 + (n0 & 63);
    ld = 64;
  } else {
    Wl = W + (size_t)l * K * N + n0;
    ld = N;
  }
  #pragma unroll
  for (int i = 0; i < 4; ++i)
    tile[ty + 8 * i][tx] = Wl[(size_t)(k0 + ty + 8 * i) * ld + tx];
  __syncthreads();
  u16* out = BT + (size_t)l * lstride;
  #pragma unroll
  for (int i = 0; i < 4; ++i)
    out[(size_t)(n0 + ty + 8 * i) * K + k0 + tx] = f2bf(tile[tx][ty + 8 * i]);
}

// ---------------------------------------------------------------------------
// bf16 MFMA GEMM (m97 structure + G4 chunk-XOR swizzle): 128x128 tile, BK=64,
// 4 waves.  LDS rows are 128B (8 x 16B chunks); stored chunk = c ^ (row&7),
// applied as pre-swizzled global source (stage) + XOR'd read offset.
// ---------------------------------------------------------------------------
template <bool BIAS, bool RELU, bool RESID, bool OBF16>
__global__ __launch_bounds__(256) void gemm_mfma(
    const u16* __restrict__ A, const u16* __restrict__ BT,
    const float* __restrict__ bias, const float* __restrict__ resid,
    void* __restrict__ Cv, int M, int N, int K) {
  __shared__ u16 As[128 * 64];
  __shared__ u16 Bs[128 * 64];
  const int tid = threadIdx.x;
  const int lane = tid & 63, wave = tid >> 6;
  const int m0 = blockIdx.x * 128, n0 = blockIdx.y * 128;
  const int wr = (wave >> 1) * 64, wc = (wave & 1) * 64;
  const int srow = tid >> 3;
  // pre-swizzled source chunk: sc ^ (srow & 7)
  const int scol = (((tid & 7) ^ (srow & 7)) * 8);
  const u16* Ag = A + (size_t)(m0 + srow) * K + scol;
  const u16* Bg = BT + (size_t)(n0 + srow) * K + scol;

  f32x4 acc[4][4] = {};
  for (int k0 = 0; k0 < K; k0 += 64) {
    #pragma unroll
    for (int c = 0; c < 4; ++c) {
      __builtin_amdgcn_global_load_lds(
          (const guint*)(Ag + k0 + (size_t)c * 32 * K),
          (luint*)(As + c * 2048 + tid * 8), 16, 0, 0);
      __builtin_amdgcn_global_load_lds(
          (const guint*)(Bg + k0 + (size_t)c * 32 * K),
          (luint*)(Bs + c * 2048 + tid * 8), 16, 0, 0);
    }
    __syncthreads();
    #pragma unroll
    for (int kk = 0; kk < 64; kk += 32) {
      // read chunk = ((kk>>3)|g) ^ (lane&7); row swizzle bits reduce to lane&7
      const int chA = (((kk >> 3) | (lane >> 4)) ^ (lane & 7)) * 8;
      short8v av[4], bv[4];
      #pragma unroll
      for (int i = 0; i < 4; ++i)
        av[i] = *(const short8v*)(As + (wr + i * 16 + (lane & 15)) * 64 + chA);
      #pragma unroll
      for (int j = 0; j < 4; ++j)
        bv[j] = *(const short8v*)(Bs + (wc + j * 16 + (lane & 15)) * 64 + chA);
      #pragma unroll
      for (int i = 0; i < 4; ++i)
        #pragma unroll
        for (int j = 0; j < 4; ++j)
          acc[i][j] = __builtin_amdgcn_mfma_f32_16x16x32_bf16(av[i], bv[j], acc[i][j], 0, 0, 0);
    }
    __syncthreads();
  }
  #pragma unroll
  for (int i = 0; i < 4; ++i) {
    #pragma unroll
    for (int j = 0; j < 4; ++j) {
      const int col = n0 + wc + j * 16 + (lane & 15);
      #pragma unroll
      for (int r = 0; r < 4; ++r) {
        const int row = m0 + wr + i * 16 + (lane >> 4) * 4 + r;
        float v = acc[i][j][r];
        if (BIAS) v += bias[col];
        if (RELU) v = fmaxf(v, 0.f);
        if (RESID) v += resid[(size_t)row * N + col];
        if (OBF16)
          ((u16*)Cv)[(size_t)row * N + col] = f2bf(v);
        else
          ((float*)Cv)[(size_t)row * N + col] = v;
      }
    }
  }
}

// ---------------------------------------------------------------------------
// 8-phase 256x256 GEMM (T3/T4 counted-vmcnt + T5 setprio + chunk-XOR swizzle).
// LDS regions: [2 buf][2 k-half] of 256r x 32c bf16 (64B rows, 4 x 16B chunks).
// Stored chunk = c ^ ((row>>1)&3)  -> 8 distinct bank windows per 16 lanes
// (2-way, free).  Source pre-swizzled; read offset XOR'd (reduces to
// (lane>>1)&3 per-lane constant).
// ---------------------------------------------------------------------------
#define LDA_(BUF, KH, F) \
  (*(const short8v*)&As[BUF][KH][(wm * 128 + (F) * 16 + (lane & 15)) * 32 + rg])
#define LDB_(BUF, KH, NF) \
  (*(const short8v*)&Bs[BUF][KH][(wn * 64 + (NF) * 16 + (lane & 15)) * 32 + rg])
#define PH_A(BUF, KH, FB) { a0 = LDA_(BUF, KH, (FB) + 0); a1 = LDA_(BUF, KH, (FB) + 1); \
                            a2 = LDA_(BUF, KH, (FB) + 2); a3 = LDA_(BUF, KH, (FB) + 3); }
#define PH_B(BUF, KH)     { b0 = LDB_(BUF, KH, 0); b1 = LDB_(BUF, KH, 1); \
                            b2 = LDB_(BUF, KH, 2); b3 = LDB_(BUF, KH, 3); }
#define STAGE_A(BUF, KH, KT) do { \
  __builtin_amdgcn_global_load_lds((const guint*)(Abase + (KT) * 64 + (KH) * 32), \
      (luint*)(&As[BUF][KH][tid * 8]), 16, 0, 0); \
  __builtin_amdgcn_global_load_lds((const guint*)(Abase + (size_t)128 * K + (KT) * 64 + (KH) * 32), \
      (luint*)(&As[BUF][KH][(tid + 512) * 8]), 16, 0, 0); \
} while (0)
#define STAGE_B(BUF, KH, KT) do { \
  __builtin_amdgcn_global_load_lds((const guint*)(Bbase + (KT) * 64 + (KH) * 32), \
      (luint*)(&Bs[BUF][KH][tid * 8]), 16, 0, 0); \
  __builtin_amdgcn_global_load_lds((const guint*)(Bbase + (size_t)128 * K + (KT) * 64 + (KH) * 32), \
      (luint*)(&Bs[BUF][KH][(tid + 512) * 8]), 16, 0, 0); \
} while (0)
#define MFMA_ROW(F, AQ) \
  acc[F][0] = __builtin_amdgcn_mfma_f32_16x16x32_bf16(AQ, b0, acc[F][0], 0, 0, 0); \
  acc[F][1] = __builtin_amdgcn_mfma_f32_16x16x32_bf16(AQ, b1, acc[F][1], 0, 0, 0); \
  acc[F][2] = __builtin_amdgcn_mfma_f32_16x16x32_bf16(AQ, b2, acc[F][2], 0, 0, 0); \
  acc[F][3] = __builtin_amdgcn_mfma_f32_16x16x32_bf16(AQ, b3, acc[F][3], 0, 0, 0);
#define MFMA16(FB) MFMA_ROW((FB) + 0, a0) MFMA_ROW((FB) + 1, a1) \
                   MFMA_ROW((FB) + 2, a2) MFMA_ROW((FB) + 3, a3)
#define BARRIER __builtin_amdgcn_s_barrier()
#define LGKM0 asm volatile("s_waitcnt lgkmcnt(0)" ::: "memory")
#define MEMFENCE asm volatile("" ::: "memory")

#define TILE8(CUR, KT, ST1, ST2, V1STR, DOV3, V3STR) { \
  const int cur_ = (CUR); \
  MEMFENCE; \
  PH_B(cur_, 0); PH_A(cur_, 0, 0); \
  if (ST1) { STAGE_A(cur_ ^ 1, 1, (KT) + 1); } \
  BARRIER; LGKM0; \
  __builtin_amdgcn_s_setprio(1); MFMA16(0); __builtin_amdgcn_s_setprio(0); \
  BARRIER; MEMFENCE; \
  PH_A(cur_, 0, 4); \
  if (ST1) { STAGE_B(cur_ ^ 1, 1, (KT) + 1); } \
  asm volatile("s_waitcnt " V1STR ::: "memory"); \
  BARRIER; LGKM0; \
  __builtin_amdgcn_s_setprio(1); MFMA16(4); __builtin_amdgcn_s_setprio(0); \
  BARRIER; MEMFENCE; \
  PH_B(cur_, 1); PH_A(cur_, 1, 0); \
  if (ST2) { STAGE_A(cur_, 0, (KT) + 2); } \
  BARRIER; LGKM0; \
  __builtin_amdgcn_s_setprio(1); MFMA16(0); __builtin_amdgcn_s_setprio(0); \
  BARRIER; MEMFENCE; \
  PH_A(cur_, 1, 4); \
  if (ST2) { STAGE_B(cur_, 0, (KT) + 2); } \
  if (DOV3) { asm volatile("s_waitcnt " V3STR ::: "memory"); } \
  BARRIER; LGKM0; \
  __builtin_amdgcn_s_setprio(1); MFMA16(4); __builtin_amdgcn_s_setprio(0); \
  BARRIER; \
}

template <bool BIAS, bool RELU, bool RESID, bool OBF16>
__global__ __launch_bounds__(512, 2) void gemm8(
    const u16* __restrict__ A, const u16* __restrict__ BT,
    const float* __restrict__ bias, const float* __restrict__ resid,
    void* __restrict__ Cv, int M, int N, int K) {
  __shared__ u16 As[2][2][8192];
  __shared__ u16 Bs[2][2][8192];
  const int tid = threadIdx.x;
  const int lane = tid & 63, wave = tid >> 6;
  const int wm = wave >> 2, wn = wave & 3;
  const int nwg = gridDim.x;
  const int bid = blockIdx.x;
  const int wg = ((nwg & 7) == 0) ? ((bid & 7) * (nwg >> 3) + (bid >> 3)) : bid;
  const int nmt = M >> 8;
  const int m0 = (wg % nmt) * 256;
  const int n0 = (wg / nmt) * 256;
  const int NT = K >> 6;
  const int sr = tid >> 2;       // staging row (+0 / +128)
  // pre-swizzled source chunk: (tid&3) ^ ((sr>>1)&3)
  const int ssc = (((tid & 3) ^ ((tid >> 3) & 3)) * 8);
  const u16* Abase = A + (size_t)(m0 + sr) * K + ssc;
  const u16* Bbase = BT + (size_t)(n0 + sr) * K + ssc;
  // read chunk XOR (per-lane constant): g ^ ((lane>>1)&3), in elements
  const int rg = (((lane >> 4) ^ ((lane >> 1) & 3)) * 8);

  f32x4 acc[8][4] = {};
  short8v a0, a1, a2, a3, b0, b1, b2, b3;

  // Prologue: tile0 (both k-halves) + tile1 k0; validate tile0 k0.
  STAGE_A(0, 0, 0); STAGE_B(0, 0, 0);
  STAGE_A(0, 1, 0); STAGE_B(0, 1, 0);
  STAGE_A(1, 0, 1); STAGE_B(1, 0, 1);
  asm volatile("s_waitcnt vmcnt(8)" ::: "memory");
  BARRIER;

  int kt = 0;
  for (; kt < NT - 2; ++kt) {
    TILE8(kt & 1, kt, true, true, "vmcnt(8)", true, "vmcnt(8)");
  }
  TILE8(kt & 1, kt, true, false, "vmcnt(8)", true, "vmcnt(4)");
  ++kt;
  TILE8(kt & 1, kt, false, false, "vmcnt(0)", false, "vmcnt(0)");

  // Epilogue
  #pragma unroll
  for (int f = 0; f < 8; ++f) {
    #pragma unroll
    for (int n = 0; n < 4; ++n) {
      const int col = n0 + wn * 64 + n * 16 + (lane & 15);
      #pragma unroll
      for (int r = 0; r < 4; ++r) {
        const int row = m0 + wm * 128 + f * 16 + (lane >> 4) * 4 + r;
        float v = acc[f][n][r];
        if (BIAS) v += bias[col];
        if (RELU) v = fmaxf(v, 0.f);
        if (RESID) v += resid[(size_t)row * N + col];
        if (OBF16)
          ((u16*)Cv)[(size_t)row * N + col] = f2bf(v);
        else
          ((float*)Cv)[(size_t)row * N + col] = v;
      }
    }
  }
}

// ---------------------------------------------------------------------------
// Fallback fp32 GEMM for LM head (A bf16, B fp32 [K][N], +bias)
// ---------------------------------------------------------------------------
__global__ __launch_bounds__(256) void gemm_fb(
    const u16* __restrict__ A, const float* __restrict__ B,
    const float* __restrict__ bias, float* __restrict__ C, int M, int N, int K) {
  __shared__ alignas(16) float Asm[16][68];
  __shared__ alignas(16) float Bsm[16][68];
  const int tid = threadIdx.x;
  const int tx = tid & 15, ty = tid >> 4;
  const int m0 = blockIdx.y * 64, n0 = blockIdx.x * 64;
  const int ar = tid >> 2, ac = (tid & 3) * 4;
  const int br = tid >> 4, bc = (tid & 15) * 4;
  float acc[4][4] = {};
  for (int k0 = 0; k0 < K; k0 += 16) {
    ushort4 au = *(const ushort4*)(A + (size_t)(m0 + ar) * K + k0 + ac);
    float4 bv = *(const float4*)(B + (size_t)(k0 + br) * N + n0 + bc);
    Asm[ac + 0][ar] = bf2f_lo(au.x);
    Asm[ac + 1][ar] = bf2f_lo(au.y);
    Asm[ac + 2][ar] = bf2f_lo(au.z);
    Asm[ac + 3][ar] = bf2f_lo(au.w);
    *(float4*)&Bsm[br][bc] = bv;
    __syncthreads();
    #pragma unroll
    for (int kk = 0; kk < 16; ++kk) {
      float4 a = *(const float4*)&Asm[kk][ty * 4];
      float4 b = *(const float4*)&Bsm[kk][tx * 4];
      acc[0][0] += a.x * b.x; acc[0][1] += a.x * b.y; acc[0][2] += a.x * b.z; acc[0][3] += a.x * b.w;
      acc[1][0] += a.y * b.x; acc[1][1] += a.y * b.y; acc[1][2] += a.y * b.z; acc[1][3] += a.y * b.w;
      acc[2][0] += a.z * b.x; acc[2][1] += a.z * b.y; acc[2][2] += a.z * b.z; acc[2][3] += a.z * b.w;
      acc[3][0] += a.w * b.x; acc[3][1] += a.w * b.y; acc[3][2] += a.w * b.z; acc[3][3] += a.w * b.w;
    }
    __syncthreads();
  }
  #pragma unroll
  for (int i = 0; i < 4; ++i) {
    const int m = m0 + ty * 4 + i;
    #pragma unroll
    for (int j = 0; j < 4; ++j) {
      const int n = n0 + tx * 4 + j;
      C[(size_t)m * N + n] = acc[i][j] + bias[n];
    }
  }
}

// ---------------------------------------------------------------------------
// MFMA flash attention — q/k interleaved in qkb:
// qk[b*S+s][0..1023]=Q heads, [1024..2047]=K heads (row stride 2048).
// vt: [h*64+e][b*S+s] bf16 (stride MM).
// ---------------------------------------------------------------------------
__global__ __launch_bounds__(256) void attn_mfma(
    const u16* __restrict__ qk, const u16* __restrict__ vt,
    u16* __restrict__ o) {
  __shared__ alignas(16) u16 Ksh[64 * 64];
  __shared__ alignas(16) u16 Vsh[64 * 64];
  __shared__ unsigned Plds[4][16 * 41];
  __shared__ float bcast[4][16];
  const int tid = threadIdx.x;
  const int lane = tid & 63, wave = tid >> 6;
  const int g = lane >> 4, qi = lane & 15;
  const int qt = blockIdx.x, h = blockIdx.y, b = blockIdx.z;
  const int q0w = qt * 64 + wave * 16;
  const int qloc = wave * 16 + qi;

  short8v qf0, qf1;
  {
    const u16* qp = qk + ((size_t)b * SS + q0w + qi) * 2048 + h * DHH + g * 8;
    qf0 = *(const short8v*)qp;
    qf1 = *(const short8v*)(qp + 32);
  }

  f32x4 oacc[4] = {};
  float mrow = -1e30f, lrow = 0.f;

  for (int kt = 0; kt <= qt; ++kt) {
    __syncthreads();
    #pragma unroll
    for (int u = 0; u < 2; ++u) {
      const int unit = tid + 256 * u;
      const int row = unit >> 3, ch = unit & 7;
      const int sch = ch ^ (row & 7);
      __builtin_amdgcn_global_load_lds(
          (const guint*)(qk + ((size_t)b * SS + kt * 64 + row) * 2048 + 1024 + h * DHH + sch * 8),
          (luint*)(Ksh + unit * 8), 16, 0, 0);
      __builtin_amdgcn_global_load_lds(
          (const guint*)(vt + ((size_t)(h * DHH + row)) * MM + b * SS + kt * 64 + sch * 8),
          (luint*)(Vsh + unit * 8), 16, 0, 0);
    }
    __syncthreads();

    f32x4 st[4] = {};
    #pragma unroll
    for (int t = 0; t < 4; ++t) {
      const int row = t * 16 + qi;
      const int swz = (row & 7) << 4;
      short8v kf0 = *(const short8v*)(Ksh + row * 64 + (((g * 16) ^ swz) >> 1));
      short8v kf1 = *(const short8v*)(Ksh + row * 64 + (((64 + g * 16) ^ swz) >> 1));
      st[t] = __builtin_amdgcn_mfma_f32_16x16x32_bf16(kf0, qf0, st[t], 0, 0, 0);
      st[t] = __builtin_amdgcn_mfma_f32_16x16x32_bf16(kf1, qf1, st[t], 0, 0, 0);
    }

    if (kt == qt) {
      #pragma unroll
      for (int t = 0; t < 4; ++t)
        #pragma unroll
        for (int r = 0; r < 4; ++r)
          if (t * 16 + 4 * g + r > qloc) st[t][r] = -1e30f;
    }

    float mt = st[0][0];
    #pragma unroll
    for (int t = 0; t < 4; ++t)
      #pragma unroll
      for (int r = 0; r < 4; ++r) mt = fmaxf(mt, st[t][r]);
    mt = fmaxf(mt, __shfl_xor(mt, 16));
    mt = fmaxf(mt, __shfl_xor(mt, 32));
    const float mnew = fmaxf(mrow, mt * 0.125f);
    const float corr = __expf(mrow - mnew);
    float pl = 0.f;
    #pragma unroll
    for (int t = 0; t < 4; ++t) {
      #pragma unroll
      for (int r2 = 0; r2 < 2; ++r2) {
        float plo = __expf(fmaf(st[t][2 * r2], 0.125f, -mnew));
        float phi = __expf(fmaf(st[t][2 * r2 + 1], 0.125f, -mnew));
        pl += plo + phi;
        Plds[wave][qi * 41 + 8 * t + 2 * g + r2] =
            (unsigned)f2bf(plo) | ((unsigned)f2bf(phi) << 16);
      }
    }
    pl += __shfl_xor(pl, 16);
    pl += __shfl_xor(pl, 32);
    lrow = lrow * corr + pl;
    mrow = mnew;

    if (g == 0) bcast[wave][qi] = corr;
    float c0 = bcast[wave][g * 4 + 0];
    float c1 = bcast[wave][g * 4 + 1];
    float c2 = bcast[wave][g * 4 + 2];
    float c3 = bcast[wave][g * 4 + 3];
    #pragma unroll
    for (int dvt = 0; dvt < 4; ++dvt) {
      oacc[dvt][0] *= c0; oacc[dvt][1] *= c1;
      oacc[dvt][2] *= c2; oacc[dvt][3] *= c3;
    }

    union U8 { unsigned u[4]; short8v s8; };
    U8 pa0, pa1;
    #pragma unroll
    for (int c = 0; c < 4; ++c) {
      pa0.u[c] = Plds[wave][qi * 41 + g * 4 + c];
      pa1.u[c] = Plds[wave][qi * 41 + 16 + g * 4 + c];
    }
    #pragma unroll
    for (int dvt = 0; dvt < 4; ++dvt) {
      const int row = dvt * 16 + qi;
      const int swz = (row & 7) << 4;
      short8v v0 = *(const short8v*)(Vsh + row * 64 + (((g * 16) ^ swz) >> 1));
      short8v v1 = *(const short8v*)(Vsh + row * 64 + (((64 + g * 16) ^ swz) >> 1));
      oacc[dvt] = __builtin_amdgcn_mfma_f32_16x16x32_bf16(pa0.s8, v0, oacc[dvt], 0, 0, 0);
      oacc[dvt] = __builtin_amdgcn_mfma_f32_16x16x32_bf16(pa1.s8, v1, oacc[dvt], 0, 0, 0);
    }
  }

  if (g == 0) bcast[wave][qi] = 1.f / lrow;
  float i0 = bcast[wave][g * 4 + 0];
  float i1 = bcast[wave][g * 4 + 1];
  float i2 = bcast[wave][g * 4 + 2];
  float i3 = bcast[wave][g * 4 + 3];
  #pragma unroll
  for (int dvt = 0; dvt < 4; ++dvt) {
    const int col = h * DHH + dvt * 16 + qi;
    o[((size_t)b * SS + q0w + g * 4 + 0) * DD + col] = f2bf(oacc[dvt][0] * i0);
    o[((size_t)b * SS + q0w + g * 4 + 1) * DD + col] = f2bf(oacc[dvt][1] * i1);
    o[((size_t)b * SS + q0w + g * 4 + 2) * DD + col] = f2bf(oacc[dvt][2] * i2);
    o[((size_t)b * SS + q0w + g * 4 + 3) * DD + col] = f2bf(oacc[dvt][3] * i3);
  }
}

// ---------------------------------------------------------------------------
extern "C" void kernel_launch(void* const* d_in, const int* in_sizes, int n_in,
                              void* d_out, int out_size, void* d_ws, size_t ws_size,
                              hipStream_t stream) {
  const int* idx = (const int*)d_in[0];
  const float* tok_emb = (const float*)d_in[1];
  const float* pos_emb = (const float*)d_in[2];
  const float* ln1_s = (const float*)d_in[3];
  const float* ln1_b = (const float*)d_in[4];
  const float* wq = (const float*)d_in[5];
  const float* wk = (const float*)d_in[6];
  const float* wv = (const float*)d_in[7];
  const float* wproj = (const float*)d_in[8];
  const float* ln2_s = (const float*)d_in[9];
  const float* ln2_b = (const float*)d_in[10];
  const float* w1 = (const float*)d_in[11];
  const float* b1 = (const float*)d_in[12];
  const float* w2 = (const float*)d_in[13];
  const float* b2 = (const float*)d_in[14];
  const float* lnf_s = (const float*)d_in[15];
  const float* lnf_b = (const float*)d_in[16];
  const float* lm_w = (const float*)d_in[17];
  const float* lm_b = (const float*)d_in[18];

  const size_t MD = (size_t)MM * DD;

  // d_out scratch (dead before the LM GEMM writes d_out)
  u16* sc0 = (u16*)d_out;
  u16* BTqk = sc0;                                   // LL x [2048][1024]
  u16* BTv = BTqk + (size_t)LL * 2048 * DD;
  u16* BTp = BTv + (size_t)LL * DD * DD;
  u16* BTw1 = BTp + (size_t)LL * DD * DD;
  u16* BTw2 = BTw1 + (size_t)LL * DD * 4 * DD;
  u16* qkb = BTw2 + (size_t)LL * DD * 4 * DD;        // [M][2048]
  u16* vtb = qkb + (size_t)MM * 2048;                // [1024][4096]
  u16* ob = vtb + MD;
  u16* tmp = ob + MD;                                // [M][4096]

  // d_ws: x fp32 (16MB) + h bf16 (8MB) + BT(lm_w) bf16 (65.5MB) if room
  float* x = (float*)d_ws;
  u16* h = (u16*)((char*)d_ws + MD * 4);
  u16* BTlm = (u16*)((char*)d_ws + MD * 4 + MD * 2);
  const bool big_ws = ws_size >= (MD * 4 + MD * 2 + (size_t)VV * DD * 2);

  const dim3 blk(256);

  convT_kernel<true><<<dim3(DD / 32, DD / 32, LL), blk, 0, stream>>>(
      wq, BTqk, DD, DD, (size_t)2048 * DD);
  convT_kernel<true><<<dim3(DD / 32, DD / 32, LL), blk, 0, stream>>>(
      wk, BTqk + (size_t)DD * DD, DD, DD, (size_t)2048 * DD);
  convT_kernel<true><<<dim3(DD / 32, DD / 32, LL), blk, 0, stream>>>(
      wv, BTv, DD, DD, (size_t)DD * DD);
  convT_kernel<false><<<dim3(DD / 32, DD / 32, LL), blk, 0, stream>>>(
      wproj, BTp, DD, DD, (size_t)DD * DD);
  convT_kernel<false><<<dim3(4 * DD / 32, DD / 32, LL), blk, 0, stream>>>(
      w1, BTw1, DD, 4 * DD, (size_t)DD * 4 * DD);
  convT_kernel<false><<<dim3(DD / 32, 4 * DD / 32, LL), blk, 0, stream>>>(
      w2, BTw2, 4 * DD, DD, (size_t)4 * DD * DD);
  if (big_ws)
    convT_kernel<false><<<dim3(VV / 32, DD / 32, 1), blk, 0, stream>>>(
        lm_w, BTlm, DD, VV, (size_t)VV * DD);

  embed_kernel<<<(MM * DD / 4 + 255) / 256, blk, 0, stream>>>(idx, tok_emb, pos_emb, x);

  for (int l = 0; l < LL; ++l) {
    ln_bf16_kernel<<<MM, blk, 0, stream>>>(x, ln1_s + l * DD, ln1_b + l * DD, h);
    // Fused Q+K (8-phase): C = h @ [Wq|Wk], N=2048
    gemm8<false, false, false, true><<<dim3((MM / 256) * (2048 / 256)), dim3(512), 0, stream>>>(
        h, BTqk + (size_t)l * 2048 * DD, nullptr, nullptr, qkb, MM, 2048, DD);
    // V transposed: C[dv][s] = Wv^T . h^T
    gemm_mfma<false, false, false, true><<<dim3(DD / 128, MM / 128), blk, 0, stream>>>(
        BTv + (size_t)l * DD * DD, h, nullptr, nullptr, vtb, DD, MM, DD);
    attn_mfma<<<dim3(SS / 64, HH, BB), blk, 0, stream>>>(qkb, vtb, ob);
    gemm_mfma<false, false, true, false><<<dim3(MM / 128, DD / 128), blk, 0, stream>>>(
        ob, BTp + (size_t)l * DD * DD, nullptr, x, x, MM, DD, DD);
    ln_bf16_kernel<<<MM, blk, 0, stream>>>(x, ln2_s + l * DD, ln2_b + l * DD, h);
    // MLP1 (8-phase)
    gemm8<true, true, false, true><<<dim3((MM / 256) * (4 * DD / 256)), dim3(512), 0, stream>>>(
        h, BTw1 + (size_t)l * DD * 4 * DD, b1 + (size_t)l * 4 * DD, nullptr, tmp,
        MM, 4 * DD, DD);
    gemm_mfma<true, false, true, false><<<dim3(MM / 128, DD / 128), blk, 0, stream>>>(
        tmp, BTw2 + (size_t)l * 4 * DD * DD, b2 + (size_t)l * DD, x, x, MM, DD, 4 * DD);
  }

  ln_bf16_kernel<<<MM, blk, 0, stream>>>(x, lnf_s, lnf_b, h);
  if (big_ws) {
    gemm8<true, false, false, false><<<dim3((MM / 256) * (VV / 256)), dim3(512), 0, stream>>>(
        h, BTlm, lm_b, nullptr, (float*)d_out, MM, VV, DD);
  } else {
    gemm_fb<<<dim3(VV / 64, MM / 64), blk, 0, stream>>>(
        h, lm_w, lm_b, (float*)d_out, MM, VV, DD);
  }
}

// Round 6
// 2714.465 us; speedup vs baseline: 10.7602x; 1.0639x over previous
//
#include <hip/hip_runtime.h>
#include <hip/hip_bf16.h>

// Model dims (fixed by reference)
#define LL 8
#define DD 1024
#define HH 16
#define DHH 64
#define SS 1024
#define BB 4
#define VV 32000
#define MM (BB * SS)   // 4096 rows

typedef unsigned short u16;
typedef __attribute__((ext_vector_type(8))) short short8v;   // 8 bf16 (4 VGPRs)
typedef __attribute__((ext_vector_type(4))) float f32x4;
typedef unsigned int __attribute__((address_space(1))) guint;
typedef unsigned int __attribute__((address_space(3))) luint;

__device__ __forceinline__ float bf2f_lo(unsigned u) { return __uint_as_float(u << 16); }
__device__ __forceinline__ u16 f2bf(float f) {
  unsigned x = __float_as_uint(f);
  return (u16)((x + 0x7fffu + ((x >> 16) & 1u)) >> 16);
}

// ---------------------------------------------------------------------------
// Embedding
// ---------------------------------------------------------------------------
__global__ __launch_bounds__(256) void embed_kernel(
    const int* __restrict__ idx, const float* __restrict__ tok,
    const float* __restrict__ pos, float* __restrict__ x) {
  int i = blockIdx.x * blockDim.x + threadIdx.x;
  int elem = i * 4;
  int row = elem / DD;
  int d = elem % DD;
  int s = row % SS;
  int t = idx[row];
  float4 tv = *(const float4*)(tok + (size_t)t * DD + d);
  float4 pv = *(const float4*)(pos + (size_t)s * DD + d);
  tv.x += pv.x; tv.y += pv.y; tv.z += pv.z; tv.w += pv.w;
  *(float4*)(x + (size_t)elem) = tv;
}

// ---------------------------------------------------------------------------
// LayerNorm over D=1024 (fp32 in, bf16 out)
// ---------------------------------------------------------------------------
__global__ __launch_bounds__(256) void ln_bf16_kernel(
    const float* __restrict__ x, const float* __restrict__ sc,
    const float* __restrict__ bi, u16* __restrict__ out) {
  const int row = blockIdx.x;
  const int tid = threadIdx.x;
  __shared__ float red[4];
  float4 v = ((const float4*)(x + (size_t)row * DD))[tid];
  float s = v.x + v.y + v.z + v.w;
  #pragma unroll
  for (int off = 32; off; off >>= 1) s += __shfl_down(s, off);
  if ((tid & 63) == 0) red[tid >> 6] = s;
  __syncthreads();
  float mean = (red[0] + red[1] + red[2] + red[3]) * (1.f / DD);
  float dx = v.x - mean, dy = v.y - mean, dz = v.z - mean, dw = v.w - mean;
  float vs = dx * dx + dy * dy + dz * dz + dw * dw;
  __syncthreads();
  #pragma unroll
  for (int off = 32; off; off >>= 1) vs += __shfl_down(vs, off);
  if ((tid & 63) == 0) red[tid >> 6] = vs;
  __syncthreads();
  float var = (red[0] + red[1] + red[2] + red[3]) * (1.f / DD);
  float rstd = rsqrtf(var + 1e-5f);
  float4 s4 = ((const float4*)sc)[tid];
  float4 b4 = ((const float4*)bi)[tid];
  ushort4 o;
  o.x = f2bf(dx * rstd * s4.x + b4.x);
  o.y = f2bf(dy * rstd * s4.y + b4.y);
  o.z = f2bf(dz * rstd * s4.z + b4.z);
  o.w = f2bf(dw * rstd * s4.w + b4.w);
  *(ushort4*)(out + (size_t)row * DD + tid * 4) = o;
}

// ---------------------------------------------------------------------------
// Weight transpose + fp32->bf16: W [l][K][N] (or head-blocked) -> BT rows [N][K]
// at BT + l*lstride.
// ---------------------------------------------------------------------------
template <bool HEADW>
__global__ __launch_bounds__(256) void convT_kernel(
    const float* __restrict__ W, u16* __restrict__ BT, int K, int N,
    size_t lstride) {
  __shared__ float tile[32][33];
  const int n0 = blockIdx.x * 32, k0 = blockIdx.y * 32, l = blockIdx.z;
  const int tx = threadIdx.x & 31, ty = threadIdx.x >> 5;
  const float* Wl;
  int ld;
  if (HEADW) {
    const int h = n0 >> 6;
    Wl = W + ((size_t)(l * HH + h) * K) * 64 + (n0 & 63);
    ld = 64;
  } else {
    Wl = W + (size_t)l * K * N + n0;
    ld = N;
  }
  #pragma unroll
  for (int i = 0; i < 4; ++i)
    tile[ty + 8 * i][tx] = Wl[(size_t)(k0 + ty + 8 * i) * ld + tx];
  __syncthreads();
  u16* out = BT + (size_t)l * lstride;
  #pragma unroll
  for (int i = 0; i < 4; ++i)
    out[(size_t)(n0 + ty + 8 * i) * K + k0 + tx] = f2bf(tile[tx][ty + 8 * i]);
}

// ---------------------------------------------------------------------------
// bf16 MFMA GEMM (m97 structure + chunk-XOR swizzle): 128x128 tile, BK=64,
// 4 waves.  Used for the small-N per-layer GEMMs (vt / proj / MLP2).
// ---------------------------------------------------------------------------
template <bool BIAS, bool RELU, bool RESID, bool OBF16>
__global__ __launch_bounds__(256) void gemm_mfma(
    const u16* __restrict__ A, const u16* __restrict__ BT,
    const float* __restrict__ bias, const float* __restrict__ resid,
    void* __restrict__ Cv, int M, int N, int K) {
  __shared__ u16 As[128 * 64];
  __shared__ u16 Bs[128 * 64];
  const int tid = threadIdx.x;
  const int lane = tid & 63, wave = tid >> 6;
  const int m0 = blockIdx.x * 128, n0 = blockIdx.y * 128;
  const int wr = (wave >> 1) * 64, wc = (wave & 1) * 64;
  const int srow = tid >> 3;
  const int scol = (((tid & 7) ^ (srow & 7)) * 8);   // pre-swizzled source chunk
  const u16* Ag = A + (size_t)(m0 + srow) * K + scol;
  const u16* Bg = BT + (size_t)(n0 + srow) * K + scol;

  f32x4 acc[4][4] = {};
  for (int k0 = 0; k0 < K; k0 += 64) {
    #pragma unroll
    for (int c = 0; c < 4; ++c) {
      __builtin_amdgcn_global_load_lds(
          (const guint*)(Ag + k0 + (size_t)c * 32 * K),
          (luint*)(As + c * 2048 + tid * 8), 16, 0, 0);
      __builtin_amdgcn_global_load_lds(
          (const guint*)(Bg + k0 + (size_t)c * 32 * K),
          (luint*)(Bs + c * 2048 + tid * 8), 16, 0, 0);
    }
    __syncthreads();
    #pragma unroll
    for (int kk = 0; kk < 64; kk += 32) {
      const int chA = (((kk >> 3) | (lane >> 4)) ^ (lane & 7)) * 8;
      short8v av[4], bv[4];
      #pragma unroll
      for (int i = 0; i < 4; ++i)
        av[i] = *(const short8v*)(As + (wr + i * 16 + (lane & 15)) * 64 + chA);
      #pragma unroll
      for (int j = 0; j < 4; ++j)
        bv[j] = *(const short8v*)(Bs + (wc + j * 16 + (lane & 15)) * 64 + chA);
      #pragma unroll
      for (int i = 0; i < 4; ++i)
        #pragma unroll
        for (int j = 0; j < 4; ++j)
          acc[i][j] = __builtin_amdgcn_mfma_f32_16x16x32_bf16(av[i], bv[j], acc[i][j], 0, 0, 0);
    }
    __syncthreads();
  }
  #pragma unroll
  for (int i = 0; i < 4; ++i) {
    #pragma unroll
    for (int j = 0; j < 4; ++j) {
      const int col = n0 + wc + j * 16 + (lane & 15);
      #pragma unroll
      for (int r = 0; r < 4; ++r) {
        const int row = m0 + wr + i * 16 + (lane >> 4) * 4 + r;
        float v = acc[i][j][r];
        if (BIAS) v += bias[col];
        if (RELU) v = fmaxf(v, 0.f);
        if (RESID) v += resid[(size_t)row * N + col];
        if (OBF16)
          ((u16*)Cv)[(size_t)row * N + col] = f2bf(v);
        else
          ((float*)Cv)[(size_t)row * N + col] = v;
      }
    }
  }
}

// ---------------------------------------------------------------------------
// Pipelined 256x256 GEMM: register-double-buffered 4-phase schedule.
// Each phase: [issue NEXT phase's ds_reads into alt frag set] [stage]
// [vmcnt(6)] [lgkmcnt(#just-issued) -> proves current frags resident]
// [barrier] [16 MFMA].  One barrier/phase; LDS drain overlaps barrier+MFMA.
// LDS: [2 buf][2 k-half] regions of 256r x 32c bf16, chunk-XOR swizzled
// (conflict-free, PMC-verified).  vmcnt FIFO: steady 10 outstanding,
// waits at ph1/ph3 = vmcnt(6); tails 6 -> 4 -> 0.
// ---------------------------------------------------------------------------
#define LDA_(BUF, KH, F) \
  (*(const short8v*)&As[BUF][KH][(wm * 128 + (F) * 16 + (lane & 15)) * 32 + rg])
#define LDB_(BUF, KH, NF) \
  (*(const short8v*)&Bs[BUF][KH][(wn * 64 + (NF) * 16 + (lane & 15)) * 32 + rg])
#define LDS_A(S0,S1,S2,S3, BUF, KH, FB) { \
  S0 = LDA_(BUF, KH, (FB) + 0); S1 = LDA_(BUF, KH, (FB) + 1); \
  S2 = LDA_(BUF, KH, (FB) + 2); S3 = LDA_(BUF, KH, (FB) + 3); }
#define LDS_B(S0,S1,S2,S3, BUF, KH) { \
  S0 = LDB_(BUF, KH, 0); S1 = LDB_(BUF, KH, 1); \
  S2 = LDB_(BUF, KH, 2); S3 = LDB_(BUF, KH, 3); }
#define STAGE_A(BUF, KH, KT) do { \
  __builtin_amdgcn_global_load_lds((const guint*)(Abase + (KT) * 64 + (KH) * 32), \
      (luint*)(&As[BUF][KH][tid * 8]), 16, 0, 0); \
  __builtin_amdgcn_global_load_lds((const guint*)(Abase + (size_t)128 * K + (KT) * 64 + (KH) * 32), \
      (luint*)(&As[BUF][KH][(tid + 512) * 8]), 16, 0, 0); \
} while (0)
#define STAGE_B(BUF, KH, KT) do { \
  __builtin_amdgcn_global_load_lds((const guint*)(Bbase + (KT) * 64 + (KH) * 32), \
      (luint*)(&Bs[BUF][KH][tid * 8]), 16, 0, 0); \
  __builtin_amdgcn_global_load_lds((const guint*)(Bbase + (size_t)128 * K + (KT) * 64 + (KH) * 32), \
      (luint*)(&Bs[BUF][KH][(tid + 512) * 8]), 16, 0, 0); \
} while (0)
#define MROW(F, AQ, B0,B1,B2,B3) \
  acc[F][0] = __builtin_amdgcn_mfma_f32_16x16x32_bf16(AQ, B0, acc[F][0], 0, 0, 0); \
  acc[F][1] = __builtin_amdgcn_mfma_f32_16x16x32_bf16(AQ, B1, acc[F][1], 0, 0, 0); \
  acc[F][2] = __builtin_amdgcn_mfma_f32_16x16x32_bf16(AQ, B2, acc[F][2], 0, 0, 0); \
  acc[F][3] = __builtin_amdgcn_mfma_f32_16x16x32_bf16(AQ, B3, acc[F][3], 0, 0, 0);
#define MFMA16S(FB, A0,A1,A2,A3, B0,B1,B2,B3) \
  MROW((FB) + 0, A0, B0,B1,B2,B3) MROW((FB) + 1, A1, B0,B1,B2,B3) \
  MROW((FB) + 2, A2, B0,B1,B2,B3) MROW((FB) + 3, A3, B0,B1,B2,B3)
#define BARRIER __builtin_amdgcn_s_barrier()
#define MEMFENCE asm volatile("" ::: "memory")

#define TILE4(CUR, KT, ST1, ST2, V1STR, V3STR, LD4, LGK4STR) { \
  const int cur_ = (CUR); \
  /* ph1: MFMA acc[0..3] (aP,bP)[kh0]; load aN = A(kh0,f4-7) */ \
  MEMFENCE; \
  LDS_A(aN0,aN1,aN2,aN3, cur_, 0, 4); \
  if (ST1) { STAGE_A(cur_ ^ 1, 1, (KT) + 1); } \
  asm volatile("s_waitcnt " V1STR ::: "memory"); \
  asm volatile("s_waitcnt lgkmcnt(4)" ::: "memory"); \
  BARRIER; \
  __builtin_amdgcn_s_setprio(1); \
  MFMA16S(0, aP0,aP1,aP2,aP3, bP0,bP1,bP2,bP3); \
  __builtin_amdgcn_s_setprio(0); \
  /* ph2: MFMA acc[4..7] (aN,bP); load aP = A(kh1,f0-3), bN = B(kh1) */ \
  MEMFENCE; \
  LDS_A(aP0,aP1,aP2,aP3, cur_, 1, 0); \
  LDS_B(bN0,bN1,bN2,bN3, cur_, 1); \
  if (ST1) { STAGE_B(cur_ ^ 1, 1, (KT) + 1); } \
  asm volatile("s_waitcnt lgkmcnt(8)" ::: "memory"); \
  BARRIER; \
  __builtin_amdgcn_s_setprio(1); \
  MFMA16S(4, aN0,aN1,aN2,aN3, bP0,bP1,bP2,bP3); \
  __builtin_amdgcn_s_setprio(0); \
  /* ph3: MFMA acc[0..3] (aP,bN)[kh1]; load aN = A(kh1,f4-7) */ \
  MEMFENCE; \
  LDS_A(aN0,aN1,aN2,aN3, cur_, 1, 4); \
  if (ST2) { STAGE_A(cur_, 0, (KT) + 2); } \
  asm volatile("s_waitcnt " V3STR ::: "memory"); \
  asm volatile("s_waitcnt lgkmcnt(4)" ::: "memory"); \
  BARRIER; \
  __builtin_amdgcn_s_setprio(1); \
  MFMA16S(0, aP0,aP1,aP2,aP3, bN0,bN1,bN2,bN3); \
  __builtin_amdgcn_s_setprio(0); \
  /* ph4: MFMA acc[4..7] (aN,bN); load aP,bP = next tile kh0 */ \
  MEMFENCE; \
  if (LD4) { LDS_A(aP0,aP1,aP2,aP3, cur_ ^ 1, 0, 0); \
             LDS_B(bP0,bP1,bP2,bP3, cur_ ^ 1, 0); } \
  if (ST2) { STAGE_B(cur_, 0, (KT) + 2); } \
  asm volatile("s_waitcnt " LGK4STR ::: "memory"); \
  BARRIER; \
  __builtin_amdgcn_s_setprio(1); \
  MFMA16S(4, aN0,aN1,aN2,aN3, bN0,bN1,bN2,bN3); \
  __builtin_amdgcn_s_setprio(0); \
}

template <bool BIAS, bool RELU, bool RESID, bool OBF16>
__global__ __launch_bounds__(512, 2) void gemm8(
    const u16* __restrict__ A, const u16* __restrict__ BT,
    const float* __restrict__ bias, const float* __restrict__ resid,
    void* __restrict__ Cv, int M, int N, int K) {
  __shared__ u16 As[2][2][8192];
  __shared__ u16 Bs[2][2][8192];
  const int tid = threadIdx.x;
  const int lane = tid & 63, wave = tid >> 6;
  const int wm = wave >> 2, wn = wave & 3;
  const int nwg = gridDim.x;
  const int bid = blockIdx.x;
  const int wg = ((nwg & 7) == 0) ? ((bid & 7) * (nwg >> 3) + (bid >> 3)) : bid;
  const int nmt = M >> 8;
  const int m0 = (wg % nmt) * 256;
  const int n0 = (wg / nmt) * 256;
  const int NT = K >> 6;
  const int sr = tid >> 2;
  const int ssc = (((tid & 3) ^ ((tid >> 3) & 3)) * 8);  // pre-swizzled chunk
  const u16* Abase = A + (size_t)(m0 + sr) * K + ssc;
  const u16* Bbase = BT + (size_t)(n0 + sr) * K + ssc;
  const int rg = (((lane >> 4) ^ ((lane >> 1) & 3)) * 8);  // read-chunk XOR

  f32x4 acc[8][4] = {};
  short8v aP0, aP1, aP2, aP3, aN0, aN1, aN2, aN3;
  short8v bP0, bP1, bP2, bP3, bN0, bN1, bN2, bN3;

  // Prologue: stage tile0 (both halves) + tile1 kh0; validate tile0 kh0;
  // pre-load the first phase's fragments (pseudo-ph4).
  STAGE_A(0, 0, 0); STAGE_B(0, 0, 0);
  STAGE_A(0, 1, 0); STAGE_B(0, 1, 0);
  STAGE_A(1, 0, 1); STAGE_B(1, 0, 1);
  asm volatile("s_waitcnt vmcnt(8)" ::: "memory");
  BARRIER;
  MEMFENCE;
  LDS_A(aP0,aP1,aP2,aP3, 0, 0, 0);
  LDS_B(bP0,bP1,bP2,bP3, 0, 0);

  int kt = 0;
  for (; kt < NT - 2; ++kt) {
    TILE4(kt & 1, kt, true, true, "vmcnt(6)", "vmcnt(6)", true, "lgkmcnt(8)");
  }
  TILE4(kt & 1, kt, true, false, "vmcnt(6)", "vmcnt(4)", true, "lgkmcnt(8)");
  ++kt;
  TILE4(kt & 1, kt, false, false, "vmcnt(0)", "vmcnt(0)", false, "lgkmcnt(0)");

  // Epilogue
  #pragma unroll
  for (int f = 0; f < 8; ++f) {
    #pragma unroll
    for (int n = 0; n < 4; ++n) {
      const int col = n0 + wn * 64 + n * 16 + (lane & 15);
      #pragma unroll
      for (int r = 0; r < 4; ++r) {
        const int row = m0 + wm * 128 + f * 16 + (lane >> 4) * 4 + r;
        float v = acc[f][n][r];
        if (BIAS) v += bias[col];
        if (RELU) v = fmaxf(v, 0.f);
        if (RESID) v += resid[(size_t)row * N + col];
        if (OBF16)
          ((u16*)Cv)[(size_t)row * N + col] = f2bf(v);
        else
          ((float*)Cv)[(size_t)row * N + col] = v;
      }
    }
  }
}

// ---------------------------------------------------------------------------
// Fallback fp32 GEMM for LM head (A bf16, B fp32 [K][N], +bias)
// ---------------------------------------------------------------------------
__global__ __launch_bounds__(256) void gemm_fb(
    const u16* __restrict__ A, const float* __restrict__ B,
    const float* __restrict__ bias, float* __restrict__ C, int M, int N, int K) {
  __shared__ alignas(16) float Asm[16][68];
  __shared__ alignas(16) float Bsm[16][68];
  const int tid = threadIdx.x;
  const int tx = tid & 15, ty = tid >> 4;
  const int m0 = blockIdx.y * 64, n0 = blockIdx.x * 64;
  const int ar = tid >> 2, ac = (tid & 3) * 4;
  const int br = tid >> 4, bc = (tid & 15) * 4;
  float acc[4][4] = {};
  for (int k0 = 0; k0 < K; k0 += 16) {
    ushort4 au = *(const ushort4*)(A + (size_t)(m0 + ar) * K + k0 + ac);
    float4 bv = *(const float4*)(B + (size_t)(k0 + br) * N + n0 + bc);
    Asm[ac + 0][ar] = bf2f_lo(au.x);
    Asm[ac + 1][ar] = bf2f_lo(au.y);
    Asm[ac + 2][ar] = bf2f_lo(au.z);
    Asm[ac + 3][ar] = bf2f_lo(au.w);
    *(float4*)&Bsm[br][bc] = bv;
    __syncthreads();
    #pragma unroll
    for (int kk = 0; kk < 16; ++kk) {
      float4 a = *(const float4*)&Asm[kk][ty * 4];
      float4 b = *(const float4*)&Bsm[kk][tx * 4];
      acc[0][0] += a.x * b.x; acc[0][1] += a.x * b.y; acc[0][2] += a.x * b.z; acc[0][3] += a.x * b.w;
      acc[1][0] += a.y * b.x; acc[1][1] += a.y * b.y; acc[1][2] += a.y * b.z; acc[1][3] += a.y * b.w;
      acc[2][0] += a.z * b.x; acc[2][1] += a.z * b.y; acc[2][2] += a.z * b.z; acc[2][3] += a.z * b.w;
      acc[3][0] += a.w * b.x; acc[3][1] += a.w * b.y; acc[3][2] += a.w * b.z; acc[3][3] += a.w * b.w;
    }
    __syncthreads();
  }
  #pragma unroll
  for (int i = 0; i < 4; ++i) {
    const int m = m0 + ty * 4 + i;
    #pragma unroll
    for (int j = 0; j < 4; ++j) {
      const int n = n0 + tx * 4 + j;
      C[(size_t)m * N + n] = acc[i][j] + bias[n];
    }
  }
}

// ---------------------------------------------------------------------------
// MFMA flash attention — q/k interleaved in qkb:
// qk[b*S+s][0..1023]=Q heads, [1024..2047]=K heads (row stride 2048).
// vt: [h*64+e][b*S+s] bf16 (stride MM).
// ---------------------------------------------------------------------------
__global__ __launch_bounds__(256) void attn_mfma(
    const u16* __restrict__ qk, const u16* __restrict__ vt,
    u16* __restrict__ o) {
  __shared__ alignas(16) u16 Ksh[64 * 64];
  __shared__ alignas(16) u16 Vsh[64 * 64];
  __shared__ unsigned Plds[4][16 * 41];
  __shared__ float bcast[4][16];
  const int tid = threadIdx.x;
  const int lane = tid & 63, wave = tid >> 6;
  const int g = lane >> 4, qi = lane & 15;
  const int qt = blockIdx.x, h = blockIdx.y, b = blockIdx.z;
  const int q0w = qt * 64 + wave * 16;
  const int qloc = wave * 16 + qi;

  short8v qf0, qf1;
  {
    const u16* qp = qk + ((size_t)b * SS + q0w + qi) * 2048 + h * DHH + g * 8;
    qf0 = *(const short8v*)qp;
    qf1 = *(const short8v*)(qp + 32);
  }

  f32x4 oacc[4] = {};
  float mrow = -1e30f, lrow = 0.f;

  for (int kt = 0; kt <= qt; ++kt) {
    __syncthreads();
    #pragma unroll
    for (int u = 0; u < 2; ++u) {
      const int unit = tid + 256 * u;
      const int row = unit >> 3, ch = unit & 7;
      const int sch = ch ^ (row & 7);
      __builtin_amdgcn_global_load_lds(
          (const guint*)(qk + ((size_t)b * SS + kt * 64 + row) * 2048 + 1024 + h * DHH + sch * 8),
          (luint*)(Ksh + unit * 8), 16, 0, 0);
      __builtin_amdgcn_global_load_lds(
          (const guint*)(vt + ((size_t)(h * DHH + row)) * MM + b * SS + kt * 64 + sch * 8),
          (luint*)(Vsh + unit * 8), 16, 0, 0);
    }
    __syncthreads();

    f32x4 st[4] = {};
    #pragma unroll
    for (int t = 0; t < 4; ++t) {
      const int row = t * 16 + qi;
      const int swz = (row & 7) << 4;
      short8v kf0 = *(const short8v*)(Ksh + row * 64 + (((g * 16) ^ swz) >> 1));
      short8v kf1 = *(const short8v*)(Ksh + row * 64 + (((64 + g * 16) ^ swz) >> 1));
      st[t] = __builtin_amdgcn_mfma_f32_16x16x32_bf16(kf0, qf0, st[t], 0, 0, 0);
      st[t] = __builtin_amdgcn_mfma_f32_16x16x32_bf16(kf1, qf1, st[t], 0, 0, 0);
    }

    if (kt == qt) {
      #pragma unroll
      for (int t = 0; t < 4; ++t)
        #pragma unroll
        for (int r = 0; r < 4; ++r)
          if (t * 16 + 4 * g + r > qloc) st[t][r] = -1e30f;
    }

    float mt = st[0][0];
    #pragma unroll
    for (int t = 0; t < 4; ++t)
      #pragma unroll
      for (int r = 0; r < 4; ++r) mt = fmaxf(mt, st[t][r]);
    mt = fmaxf(mt, __shfl_xor(mt, 16));
    mt = fmaxf(mt, __shfl_xor(mt, 32));
    const float mnew = fmaxf(mrow, mt * 0.125f);
    const float corr = __expf(mrow - mnew);
    float pl = 0.f;
    #pragma unroll
    for (int t = 0; t < 4; ++t) {
      #pragma unroll
      for (int r2 = 0; r2 < 2; ++r2) {
        float plo = __expf(fmaf(st[t][2 * r2], 0.125f, -mnew));
        float phi = __expf(fmaf(st[t][2 * r2 + 1], 0.125f, -mnew));
        pl += plo + phi;
        Plds[wave][qi * 41 + 8 * t + 2 * g + r2] =
            (unsigned)f2bf(plo) | ((unsigned)f2bf(phi) << 16);
      }
    }
    pl += __shfl_xor(pl, 16);
    pl += __shfl_xor(pl, 32);
    lrow = lrow * corr + pl;
    mrow = mnew;

    if (g == 0) bcast[wave][qi] = corr;
    float c0 = bcast[wave][g * 4 + 0];
    float c1 = bcast[wave][g * 4 + 1];
    float c2 = bcast[wave][g * 4 + 2];
    float c3 = bcast[wave][g * 4 + 3];
    #pragma unroll
    for (int dvt = 0; dvt < 4; ++dvt) {
      oacc[dvt][0] *= c0; oacc[dvt][1] *= c1;
      oacc[dvt][2] *= c2; oacc[dvt][3] *= c3;
    }

    union U8 { unsigned u[4]; short8v s8; };
    U8 pa0, pa1;
    #pragma unroll
    for (int c = 0; c < 4; ++c) {
      pa0.u[c] = Plds[wave][qi * 41 + g * 4 + c];
      pa1.u[c] = Plds[wave][qi * 41 + 16 + g * 4 + c];
    }
    #pragma unroll
    for (int dvt = 0; dvt < 4; ++dvt) {
      const int row = dvt * 16 + qi;
      const int swz = (row & 7) << 4;
      short8v v0 = *(const short8v*)(Vsh + row * 64 + (((g * 16) ^ swz) >> 1));
      short8v v1 = *(const short8v*)(Vsh + row * 64 + (((64 + g * 16) ^ swz) >> 1));
      oacc[dvt] = __builtin_amdgcn_mfma_f32_16x16x32_bf16(pa0.s8, v0, oacc[dvt], 0, 0, 0);
      oacc[dvt] = __builtin_amdgcn_mfma_f32_16x16x32_bf16(pa1.s8, v1, oacc[dvt], 0, 0, 0);
    }
  }

  if (g == 0) bcast[wave][qi] = 1.f / lrow;
  float i0 = bcast[wave][g * 4 + 0];
  float i1 = bcast[wave][g * 4 + 1];
  float i2 = bcast[wave][g * 4 + 2];
  float i3 = bcast[wave][g * 4 + 3];
  #pragma unroll
  for (int dvt = 0; dvt < 4; ++dvt) {
    const int col = h * DHH + dvt * 16 + qi;
    o[((size_t)b * SS + q0w + g * 4 + 0) * DD + col] = f2bf(oacc[dvt][0] * i0);
    o[((size_t)b * SS + q0w + g * 4 + 1) * DD + col] = f2bf(oacc[dvt][1] * i1);
    o[((size_t)b * SS + q0w + g * 4 + 2) * DD + col] = f2bf(oacc[dvt][2] * i2);
    o[((size_t)b * SS + q0w + g * 4 + 3) * DD + col] = f2bf(oacc[dvt][3] * i3);
  }
}

// ---------------------------------------------------------------------------
extern "C" void kernel_launch(void* const* d_in, const int* in_sizes, int n_in,
                              void* d_out, int out_size, void* d_ws, size_t ws_size,
                              hipStream_t stream) {
  const int* idx = (const int*)d_in[0];
  const float* tok_emb = (const float*)d_in[1];
  const float* pos_emb = (const float*)d_in[2];
  const float* ln1_s = (const float*)d_in[3];
  const float* ln1_b = (const float*)d_in[4];
  const float* wq = (const float*)d_in[5];
  const float* wk = (const float*)d_in[6];
  const float* wv = (const float*)d_in[7];
  const float* wproj = (const float*)d_in[8];
  const float* ln2_s = (const float*)d_in[9];
  const float* ln2_b = (const float*)d_in[10];
  const float* w1 = (const float*)d_in[11];
  const float* b1 = (const float*)d_in[12];
  const float* w2 = (const float*)d_in[13];
  const float* b2 = (const float*)d_in[14];
  const float* lnf_s = (const float*)d_in[15];
  const float* lnf_b = (const float*)d_in[16];
  const float* lm_w = (const float*)d_in[17];
  const float* lm_b = (const float*)d_in[18];

  const size_t MD = (size_t)MM * DD;

  // d_out scratch (dead before the LM GEMM writes d_out)
  u16* sc0 = (u16*)d_out;
  u16* BTqk = sc0;                                   // LL x [2048][1024]
  u16* BTv = BTqk + (size_t)LL * 2048 * DD;
  u16* BTp = BTv + (size_t)LL * DD * DD;
  u16* BTw1 = BTp + (size_t)LL * DD * DD;
  u16* BTw2 = BTw1 + (size_t)LL * DD * 4 * DD;
  u16* qkb = BTw2 + (size_t)LL * DD * 4 * DD;        // [M][2048]
  u16* vtb = qkb + (size_t)MM * 2048;                // [1024][4096]
  u16* ob = vtb + MD;
  u16* tmp = ob + MD;                                // [M][4096]

  // d_ws: x fp32 (16MB) + h bf16 (8MB) + BT(lm_w) bf16 (65.5MB) if room
  float* x = (float*)d_ws;
  u16* h = (u16*)((char*)d_ws + MD * 4);
  u16* BTlm = (u16*)((char*)d_ws + MD * 4 + MD * 2);
  const bool big_ws = ws_size >= (MD * 4 + MD * 2 + (size_t)VV * DD * 2);

  const dim3 blk(256);

  convT_kernel<true><<<dim3(DD / 32, DD / 32, LL), blk, 0, stream>>>(
      wq, BTqk, DD, DD, (size_t)2048 * DD);
  convT_kernel<true><<<dim3(DD / 32, DD / 32, LL), blk, 0, stream>>>(
      wk, BTqk + (size_t)DD * DD, DD, DD, (size_t)2048 * DD);
  convT_kernel<true><<<dim3(DD / 32, DD / 32, LL), blk, 0, stream>>>(
      wv, BTv, DD, DD, (size_t)DD * DD);
  convT_kernel<false><<<dim3(DD / 32, DD / 32, LL), blk, 0, stream>>>(
      wproj, BTp, DD, DD, (size_t)DD * DD);
  convT_kernel<false><<<dim3(4 * DD / 32, DD / 32, LL), blk, 0, stream>>>(
      w1, BTw1, DD, 4 * DD, (size_t)DD * 4 * DD);
  convT_kernel<false><<<dim3(DD / 32, 4 * DD / 32, LL), blk, 0, stream>>>(
      w2, BTw2, 4 * DD, DD, (size_t)4 * DD * DD);
  if (big_ws)
    convT_kernel<false><<<dim3(VV / 32, DD / 32, 1), blk, 0, stream>>>(
        lm_w, BTlm, DD, VV, (size_t)VV * DD);

  embed_kernel<<<(MM * DD / 4 + 255) / 256, blk, 0, stream>>>(idx, tok_emb, pos_emb, x);

  for (int l = 0; l < LL; ++l) {
    ln_bf16_kernel<<<MM, blk, 0, stream>>>(x, ln1_s + l * DD, ln1_b + l * DD, h);
    // Fused Q+K (pipelined 256^2): C = h @ [Wq|Wk], N=2048
    gemm8<false, false, false, true><<<dim3((MM / 256) * (2048 / 256)), dim3(512), 0, stream>>>(
        h, BTqk + (size_t)l * 2048 * DD, nullptr, nullptr, qkb, MM, 2048, DD);
    // V transposed: C[dv][s] = Wv^T . h^T
    gemm_mfma<false, false, false, true><<<dim3(DD / 128, MM / 128), blk, 0, stream>>>(
        BTv + (size_t)l * DD * DD, h, nullptr, nullptr, vtb, DD, MM, DD);
    attn_mfma<<<dim3(SS / 64, HH, BB), blk, 0, stream>>>(qkb, vtb, ob);
    gemm_mfma<false, false, true, false><<<dim3(MM / 128, DD / 128), blk, 0, stream>>>(
        ob, BTp + (size_t)l * DD * DD, nullptr, x, x, MM, DD, DD);
    ln_bf16_kernel<<<MM, blk, 0, stream>>>(x, ln2_s + l * DD, ln2_b + l * DD, h);
    // MLP1 (pipelined 256^2)
    gemm8<true, true, false, true><<<dim3((MM / 256) * (4 * DD / 256)), dim3(512), 0, stream>>>(
        h, BTw1 + (size_t)l * DD * 4 * DD, b1 + (size_t)l * 4 * DD, nullptr, tmp,
        MM, 4 * DD, DD);
    gemm_mfma<true, false, true, false><<<dim3(MM / 128, DD / 128), blk, 0, stream>>>(
        tmp, BTw2 + (size_t)l * 4 * DD * DD, b2 + (size_t)l * DD, x, x, MM, DD, 4 * DD);
  }

  ln_bf16_kernel<<<MM, blk, 0, stream>>>(x, lnf_s, lnf_b, h);
  if (big_ws) {
    gemm8<true, false, false, false><<<dim3((MM / 256) * (VV / 256)), dim3(512), 0, stream>>>(
        h, BTlm, lm_b, nullptr, (float*)d_out, MM, VV, DD);
  } else {
    gemm_fb<<<dim3(VV / 64, MM / 64), blk, 0, stream>>>(
        h, lm_w, lm_b, (float*)d_out, MM, VV, DD);
  }
}

// Round 7
// 2620.944 us; speedup vs baseline: 11.1441x; 1.0357x over previous
//
#include <hip/hip_runtime.h>
#include <hip/hip_bf16.h>

// Model dims (fixed by reference)
#define LL 8
#define DD 1024
#define HH 16
#define DHH 64
#define SS 1024
#define BB 4
#define VV 32000
#define MM (BB * SS)   // 4096 rows

typedef unsigned short u16;
typedef __attribute__((ext_vector_type(8))) short short8v;   // 8 bf16 (4 VGPRs)
typedef __attribute__((ext_vector_type(4))) float f32x4;
typedef unsigned int __attribute__((address_space(1))) guint;
typedef unsigned int __attribute__((address_space(3))) luint;

__device__ __forceinline__ float bf2f_lo(unsigned u) { return __uint_as_float(u << 16); }
__device__ __forceinline__ u16 f2bf(float f) {
  unsigned x = __float_as_uint(f);
  return (u16)((x + 0x7fffu + ((x >> 16) & 1u)) >> 16);
}

// ---------------------------------------------------------------------------
// Embedding
// ---------------------------------------------------------------------------
__global__ __launch_bounds__(256) void embed_kernel(
    const int* __restrict__ idx, const float* __restrict__ tok,
    const float* __restrict__ pos, float* __restrict__ x) {
  int i = blockIdx.x * blockDim.x + threadIdx.x;
  int elem = i * 4;
  int row = elem / DD;
  int d = elem % DD;
  int s = row % SS;
  int t = idx[row];
  float4 tv = *(const float4*)(tok + (size_t)t * DD + d);
  float4 pv = *(const float4*)(pos + (size_t)s * DD + d);
  tv.x += pv.x; tv.y += pv.y; tv.z += pv.z; tv.w += pv.w;
  *(float4*)(x + (size_t)elem) = tv;
}

// ---------------------------------------------------------------------------
// LayerNorm over D=1024 (fp32 in, bf16 out)
// ---------------------------------------------------------------------------
__global__ __launch_bounds__(256) void ln_bf16_kernel(
    const float* __restrict__ x, const float* __restrict__ sc,
    const float* __restrict__ bi, u16* __restrict__ out) {
  const int row = blockIdx.x;
  const int tid = threadIdx.x;
  __shared__ float red[4];
  float4 v = ((const float4*)(x + (size_t)row * DD))[tid];
  float s = v.x + v.y + v.z + v.w;
  #pragma unroll
  for (int off = 32; off; off >>= 1) s += __shfl_down(s, off);
  if ((tid & 63) == 0) red[tid >> 6] = s;
  __syncthreads();
  float mean = (red[0] + red[1] + red[2] + red[3]) * (1.f / DD);
  float dx = v.x - mean, dy = v.y - mean, dz = v.z - mean, dw = v.w - mean;
  float vs = dx * dx + dy * dy + dz * dz + dw * dw;
  __syncthreads();
  #pragma unroll
  for (int off = 32; off; off >>= 1) vs += __shfl_down(vs, off);
  if ((tid & 63) == 0) red[tid >> 6] = vs;
  __syncthreads();
  float var = (red[0] + red[1] + red[2] + red[3]) * (1.f / DD);
  float rstd = rsqrtf(var + 1e-5f);
  float4 s4 = ((const float4*)sc)[tid];
  float4 b4 = ((const float4*)bi)[tid];
  ushort4 o;
  o.x = f2bf(dx * rstd * s4.x + b4.x);
  o.y = f2bf(dy * rstd * s4.y + b4.y);
  o.z = f2bf(dz * rstd * s4.z + b4.z);
  o.w = f2bf(dw * rstd * s4.w + b4.w);
  *(ushort4*)(out + (size_t)row * DD + tid * 4) = o;
}

// ---------------------------------------------------------------------------
// Weight transpose + fp32->bf16: W [l][K][N] (or head-blocked) -> BT rows [N][K]
// at BT + l*lstride.
// ---------------------------------------------------------------------------
template <bool HEADW>
__global__ __launch_bounds__(256) void convT_kernel(
    const float* __restrict__ W, u16* __restrict__ BT, int K, int N,
    size_t lstride) {
  __shared__ float tile[32][33];
  const int n0 = blockIdx.x * 32, k0 = blockIdx.y * 32, l = blockIdx.z;
  const int tx = threadIdx.x & 31, ty = threadIdx.x >> 5;
  const float* Wl;
  int ld;
  if (HEADW) {
    const int h = n0 >> 6;
    Wl = W + ((size_t)(l * HH + h) * K) * 64 + (n0 & 63);
    ld = 64;
  } else {
    Wl = W + (size_t)l * K * N + n0;
    ld = N;
  }
  #pragma unroll
  for (int i = 0; i < 4; ++i)
    tile[ty + 8 * i][tx] = Wl[(size_t)(k0 + ty + 8 * i) * ld + tx];
  __syncthreads();
  u16* out = BT + (size_t)l * lstride;
  #pragma unroll
  for (int i = 0; i < 4; ++i)
    out[(size_t)(n0 + ty + 8 * i) * K + k0 + tx] = f2bf(tile[tx][ty + 8 * i]);
}

// ---------------------------------------------------------------------------
// V transpose: vt[dv][s] = qkv[s][2048+dv]  (bf16, 32x32 tiles)
// ---------------------------------------------------------------------------
__global__ __launch_bounds__(256) void transpose_v(
    const u16* __restrict__ qkv, u16* __restrict__ vt) {
  __shared__ u16 t[32][33];
  const int s0 = blockIdx.x * 32, d0 = blockIdx.y * 32;
  const int tx = threadIdx.x & 31, ty = threadIdx.x >> 5;
  #pragma unroll
  for (int i = 0; i < 4; ++i)
    t[ty + 8 * i][tx] = qkv[(size_t)(s0 + ty + 8 * i) * 3072 + 2048 + d0 + tx];
  __syncthreads();
  #pragma unroll
  for (int i = 0; i < 4; ++i)
    vt[(size_t)(d0 + ty + 8 * i) * MM + s0 + tx] = t[tx][ty + 8 * i];
}

// ---------------------------------------------------------------------------
// bf16 MFMA GEMM (m97 structure + chunk-XOR swizzle): 128x128 tile, BK=64,
// 4 waves.  Used for the small-N per-layer GEMMs (proj / MLP2).
// ---------------------------------------------------------------------------
template <bool BIAS, bool RELU, bool RESID, bool OBF16>
__global__ __launch_bounds__(256) void gemm_mfma(
    const u16* __restrict__ A, const u16* __restrict__ BT,
    const float* __restrict__ bias, const float* __restrict__ resid,
    void* __restrict__ Cv, int M, int N, int K) {
  __shared__ u16 As[128 * 64];
  __shared__ u16 Bs[128 * 64];
  const int tid = threadIdx.x;
  const int lane = tid & 63, wave = tid >> 6;
  const int m0 = blockIdx.x * 128, n0 = blockIdx.y * 128;
  const int wr = (wave >> 1) * 64, wc = (wave & 1) * 64;
  const int srow = tid >> 3;
  const int scol = (((tid & 7) ^ (srow & 7)) * 8);   // pre-swizzled source chunk
  const u16* Ag = A + (size_t)(m0 + srow) * K + scol;
  const u16* Bg = BT + (size_t)(n0 + srow) * K + scol;

  f32x4 acc[4][4] = {};
  for (int k0 = 0; k0 < K; k0 += 64) {
    #pragma unroll
    for (int c = 0; c < 4; ++c) {
      __builtin_amdgcn_global_load_lds(
          (const guint*)(Ag + k0 + (size_t)c * 32 * K),
          (luint*)(As + c * 2048 + tid * 8), 16, 0, 0);
      __builtin_amdgcn_global_load_lds(
          (const guint*)(Bg + k0 + (size_t)c * 32 * K),
          (luint*)(Bs + c * 2048 + tid * 8), 16, 0, 0);
    }
    __syncthreads();
    #pragma unroll
    for (int kk = 0; kk < 64; kk += 32) {
      const int chA = (((kk >> 3) | (lane >> 4)) ^ (lane & 7)) * 8;
      short8v av[4], bv[4];
      #pragma unroll
      for (int i = 0; i < 4; ++i)
        av[i] = *(const short8v*)(As + (wr + i * 16 + (lane & 15)) * 64 + chA);
      #pragma unroll
      for (int j = 0; j < 4; ++j)
        bv[j] = *(const short8v*)(Bs + (wc + j * 16 + (lane & 15)) * 64 + chA);
      #pragma unroll
      for (int i = 0; i < 4; ++i)
        #pragma unroll
        for (int j = 0; j < 4; ++j)
          acc[i][j] = __builtin_amdgcn_mfma_f32_16x16x32_bf16(av[i], bv[j], acc[i][j], 0, 0, 0);
    }
    __syncthreads();
  }
  #pragma unroll
  for (int i = 0; i < 4; ++i) {
    #pragma unroll
    for (int j = 0; j < 4; ++j) {
      const int col = n0 + wc + j * 16 + (lane & 15);
      #pragma unroll
      for (int r = 0; r < 4; ++r) {
        const int row = m0 + wr + i * 16 + (lane >> 4) * 4 + r;
        float v = acc[i][j][r];
        if (BIAS) v += bias[col];
        if (RELU) v = fmaxf(v, 0.f);
        if (RESID) v += resid[(size_t)row * N + col];
        if (OBF16)
          ((u16*)Cv)[(size_t)row * N + col] = f2bf(v);
        else
          ((float*)Cv)[(size_t)row * N + col] = v;
      }
    }
  }
}

// ---------------------------------------------------------------------------
// Pipelined 256x256 GEMM: register-double-buffered 4-phase schedule
// (as round 6, verified) + optional nontemporal C stores (NTC).
// ---------------------------------------------------------------------------
#define LDA_(BUF, KH, F) \
  (*(const short8v*)&As[BUF][KH][(wm * 128 + (F) * 16 + (lane & 15)) * 32 + rg])
#define LDB_(BUF, KH, NF) \
  (*(const short8v*)&Bs[BUF][KH][(wn * 64 + (NF) * 16 + (lane & 15)) * 32 + rg])
#define LDS_A(S0,S1,S2,S3, BUF, KH, FB) { \
  S0 = LDA_(BUF, KH, (FB) + 0); S1 = LDA_(BUF, KH, (FB) + 1); \
  S2 = LDA_(BUF, KH, (FB) + 2); S3 = LDA_(BUF, KH, (FB) + 3); }
#define LDS_B(S0,S1,S2,S3, BUF, KH) { \
  S0 = LDB_(BUF, KH, 0); S1 = LDB_(BUF, KH, 1); \
  S2 = LDB_(BUF, KH, 2); S3 = LDB_(BUF, KH, 3); }
#define STAGE_A(BUF, KH, KT) do { \
  __builtin_amdgcn_global_load_lds((const guint*)(Abase + (KT) * 64 + (KH) * 32), \
      (luint*)(&As[BUF][KH][tid * 8]), 16, 0, 0); \
  __builtin_amdgcn_global_load_lds((const guint*)(Abase + (size_t)128 * K + (KT) * 64 + (KH) * 32), \
      (luint*)(&As[BUF][KH][(tid + 512) * 8]), 16, 0, 0); \
} while (0)
#define STAGE_B(BUF, KH, KT) do { \
  __builtin_amdgcn_global_load_lds((const guint*)(Bbase + (KT) * 64 + (KH) * 32), \
      (luint*)(&Bs[BUF][KH][tid * 8]), 16, 0, 0); \
  __builtin_amdgcn_global_load_lds((const guint*)(Bbase + (size_t)128 * K + (KT) * 64 + (KH) * 32), \
      (luint*)(&Bs[BUF][KH][(tid + 512) * 8]), 16, 0, 0); \
} while (0)
#define MROW(F, AQ, B0,B1,B2,B3) \
  acc[F][0] = __builtin_amdgcn_mfma_f32_16x16x32_bf16(AQ, B0, acc[F][0], 0, 0, 0); \
  acc[F][1] = __builtin_amdgcn_mfma_f32_16x16x32_bf16(AQ, B1, acc[F][1], 0, 0, 0); \
  acc[F][2] = __builtin_amdgcn_mfma_f32_16x16x32_bf16(AQ, B2, acc[F][2], 0, 0, 0); \
  acc[F][3] = __builtin_amdgcn_mfma_f32_16x16x32_bf16(AQ, B3, acc[F][3], 0, 0, 0);
#define MFMA16S(FB, A0,A1,A2,A3, B0,B1,B2,B3) \
  MROW((FB) + 0, A0, B0,B1,B2,B3) MROW((FB) + 1, A1, B0,B1,B2,B3) \
  MROW((FB) + 2, A2, B0,B1,B2,B3) MROW((FB) + 3, A3, B0,B1,B2,B3)
#define BARRIER __builtin_amdgcn_s_barrier()
#define MEMFENCE asm volatile("" ::: "memory")

#define TILE4(CUR, KT, ST1, ST2, V1STR, V3STR, LD4, LGK4STR) { \
  const int cur_ = (CUR); \
  MEMFENCE; \
  LDS_A(aN0,aN1,aN2,aN3, cur_, 0, 4); \
  if (ST1) { STAGE_A(cur_ ^ 1, 1, (KT) + 1); } \
  asm volatile("s_waitcnt " V1STR ::: "memory"); \
  asm volatile("s_waitcnt lgkmcnt(4)" ::: "memory"); \
  BARRIER; \
  __builtin_amdgcn_s_setprio(1); \
  MFMA16S(0, aP0,aP1,aP2,aP3, bP0,bP1,bP2,bP3); \
  __builtin_amdgcn_s_setprio(0); \
  MEMFENCE; \
  LDS_A(aP0,aP1,aP2,aP3, cur_, 1, 0); \
  LDS_B(bN0,bN1,bN2,bN3, cur_, 1); \
  if (ST1) { STAGE_B(cur_ ^ 1, 1, (KT) + 1); } \
  asm volatile("s_waitcnt lgkmcnt(8)" ::: "memory"); \
  BARRIER; \
  __builtin_amdgcn_s_setprio(1); \
  MFMA16S(4, aN0,aN1,aN2,aN3, bP0,bP1,bP2,bP3); \
  __builtin_amdgcn_s_setprio(0); \
  MEMFENCE; \
  LDS_A(aN0,aN1,aN2,aN3, cur_, 1, 4); \
  if (ST2) { STAGE_A(cur_, 0, (KT) + 2); } \
  asm volatile("s_waitcnt " V3STR ::: "memory"); \
  asm volatile("s_waitcnt lgkmcnt(4)" ::: "memory"); \
  BARRIER; \
  __builtin_amdgcn_s_setprio(1); \
  MFMA16S(0, aP0,aP1,aP2,aP3, bN0,bN1,bN2,bN3); \
  __builtin_amdgcn_s_setprio(0); \
  MEMFENCE; \
  if (LD4) { LDS_A(aP0,aP1,aP2,aP3, cur_ ^ 1, 0, 0); \
             LDS_B(bP0,bP1,bP2,bP3, cur_ ^ 1, 0); } \
  if (ST2) { STAGE_B(cur_, 0, (KT) + 2); } \
  asm volatile("s_waitcnt " LGK4STR ::: "memory"); \
  BARRIER; \
  __builtin_amdgcn_s_setprio(1); \
  MFMA16S(4, aN0,aN1,aN2,aN3, bN0,bN1,bN2,bN3); \
  __builtin_amdgcn_s_setprio(0); \
}

template <bool BIAS, bool RELU, bool RESID, bool OBF16, bool NTC>
__global__ __launch_bounds__(512, 2) void gemm8(
    const u16* __restrict__ A, const u16* __restrict__ BT,
    const float* __restrict__ bias, const float* __restrict__ resid,
    void* __restrict__ Cv, int M, int N, int K) {
  __shared__ u16 As[2][2][8192];
  __shared__ u16 Bs[2][2][8192];
  const int tid = threadIdx.x;
  const int lane = tid & 63, wave = tid >> 6;
  const int wm = wave >> 2, wn = wave & 3;
  const int nwg = gridDim.x;
  const int bid = blockIdx.x;
  const int wg = ((nwg & 7) == 0) ? ((bid & 7) * (nwg >> 3) + (bid >> 3)) : bid;
  const int nmt = M >> 8;
  const int m0 = (wg % nmt) * 256;
  const int n0 = (wg / nmt) * 256;
  const int NT = K >> 6;
  const int sr = tid >> 2;
  const int ssc = (((tid & 3) ^ ((tid >> 3) & 3)) * 8);  // pre-swizzled chunk
  const u16* Abase = A + (size_t)(m0 + sr) * K + ssc;
  const u16* Bbase = BT + (size_t)(n0 + sr) * K + ssc;
  const int rg = (((lane >> 4) ^ ((lane >> 1) & 3)) * 8);  // read-chunk XOR

  f32x4 acc[8][4] = {};
  short8v aP0, aP1, aP2, aP3, aN0, aN1, aN2, aN3;
  short8v bP0, bP1, bP2, bP3, bN0, bN1, bN2, bN3;

  STAGE_A(0, 0, 0); STAGE_B(0, 0, 0);
  STAGE_A(0, 1, 0); STAGE_B(0, 1, 0);
  STAGE_A(1, 0, 1); STAGE_B(1, 0, 1);
  asm volatile("s_waitcnt vmcnt(8)" ::: "memory");
  BARRIER;
  MEMFENCE;
  LDS_A(aP0,aP1,aP2,aP3, 0, 0, 0);
  LDS_B(bP0,bP1,bP2,bP3, 0, 0);

  int kt = 0;
  for (; kt < NT - 2; ++kt) {
    TILE4(kt & 1, kt, true, true, "vmcnt(6)", "vmcnt(6)", true, "lgkmcnt(8)");
  }
  TILE4(kt & 1, kt, true, false, "vmcnt(6)", "vmcnt(4)", true, "lgkmcnt(8)");
  ++kt;
  TILE4(kt & 1, kt, false, false, "vmcnt(0)", "vmcnt(0)", false, "lgkmcnt(0)");

  #pragma unroll
  for (int f = 0; f < 8; ++f) {
    #pragma unroll
    for (int n = 0; n < 4; ++n) {
      const int col = n0 + wn * 64 + n * 16 + (lane & 15);
      #pragma unroll
      for (int r = 0; r < 4; ++r) {
        const int row = m0 + wm * 128 + f * 16 + (lane >> 4) * 4 + r;
        float v = acc[f][n][r];
        if (BIAS) v += bias[col];
        if (RELU) v = fmaxf(v, 0.f);
        if (RESID) v += resid[(size_t)row * N + col];
        if (OBF16) {
          u16 val = f2bf(v);
          if (NTC) __builtin_nontemporal_store(val, &((u16*)Cv)[(size_t)row * N + col]);
          else ((u16*)Cv)[(size_t)row * N + col] = val;
        } else {
          if (NTC) __builtin_nontemporal_store(v, &((float*)Cv)[(size_t)row * N + col]);
          else ((float*)Cv)[(size_t)row * N + col] = v;
        }
      }
    }
  }
}

// ---------------------------------------------------------------------------
// Fallback fp32 GEMM for LM head (A bf16, B fp32 [K][N], +bias)
// ---------------------------------------------------------------------------
__global__ __launch_bounds__(256) void gemm_fb(
    const u16* __restrict__ A, const float* __restrict__ B,
    const float* __restrict__ bias, float* __restrict__ C, int M, int N, int K) {
  __shared__ alignas(16) float Asm[16][68];
  __shared__ alignas(16) float Bsm[16][68];
  const int tid = threadIdx.x;
  const int tx = tid & 15, ty = tid >> 4;
  const int m0 = blockIdx.y * 64, n0 = blockIdx.x * 64;
  const int ar = tid >> 2, ac = (tid & 3) * 4;
  const int br = tid >> 4, bc = (tid & 15) * 4;
  float acc[4][4] = {};
  for (int k0 = 0; k0 < K; k0 += 16) {
    ushort4 au = *(const ushort4*)(A + (size_t)(m0 + ar) * K + k0 + ac);
    float4 bv = *(const float4*)(B + (size_t)(k0 + br) * N + n0 + bc);
    Asm[ac + 0][ar] = bf2f_lo(au.x);
    Asm[ac + 1][ar] = bf2f_lo(au.y);
    Asm[ac + 2][ar] = bf2f_lo(au.z);
    Asm[ac + 3][ar] = bf2f_lo(au.w);
    *(float4*)&Bsm[br][bc] = bv;
    __syncthreads();
    #pragma unroll
    for (int kk = 0; kk < 16; ++kk) {
      float4 a = *(const float4*)&Asm[kk][ty * 4];
      float4 b = *(const float4*)&Bsm[kk][tx * 4];
      acc[0][0] += a.x * b.x; acc[0][1] += a.x * b.y; acc[0][2] += a.x * b.z; acc[0][3] += a.x * b.w;
      acc[1][0] += a.y * b.x; acc[1][1] += a.y * b.y; acc[1][2] += a.y * b.z; acc[1][3] += a.y * b.w;
      acc[2][0] += a.z * b.x; acc[2][1] += a.z * b.y; acc[2][2] += a.z * b.z; acc[2][3] += a.z * b.w;
      acc[3][0] += a.w * b.x; acc[3][1] += a.w * b.y; acc[3][2] += a.w * b.z; acc[3][3] += a.w * b.w;
    }
    __syncthreads();
  }
  #pragma unroll
  for (int i = 0; i < 4; ++i) {
    const int m = m0 + ty * 4 + i;
    #pragma unroll
    for (int j = 0; j < 4; ++j) {
      const int n = n0 + tx * 4 + j;
      __builtin_nontemporal_store(acc[i][j] + bias[n], &C[(size_t)m * N + n]);
    }
  }
}

// ---------------------------------------------------------------------------
// MFMA flash attention — q/k/v fused in qkv rows of 3072:
// [0..1023]=Q heads, [1024..2047]=K heads, [2048..3071]=V (unused here).
// vt: [h*64+e][b*S+s] bf16 (stride MM), from transpose_v.
// ---------------------------------------------------------------------------
__global__ __launch_bounds__(256) void attn_mfma(
    const u16* __restrict__ qkv, const u16* __restrict__ vt,
    u16* __restrict__ o) {
  __shared__ alignas(16) u16 Ksh[64 * 64];
  __shared__ alignas(16) u16 Vsh[64 * 64];
  __shared__ unsigned Plds[4][16 * 41];
  __shared__ float bcast[4][16];
  const int tid = threadIdx.x;
  const int lane = tid & 63, wave = tid >> 6;
  const int g = lane >> 4, qi = lane & 15;
  const int qt = blockIdx.x, h = blockIdx.y, b = blockIdx.z;
  const int q0w = qt * 64 + wave * 16;
  const int qloc = wave * 16 + qi;

  short8v qf0, qf1;
  {
    const u16* qp = qkv + ((size_t)b * SS + q0w + qi) * 3072 + h * DHH + g * 8;
    qf0 = *(const short8v*)qp;
    qf1 = *(const short8v*)(qp + 32);
  }

  f32x4 oacc[4] = {};
  float mrow = -1e30f, lrow = 0.f;

  for (int kt = 0; kt <= qt; ++kt) {
    __syncthreads();
    #pragma unroll
    for (int u = 0; u < 2; ++u) {
      const int unit = tid + 256 * u;
      const int row = unit >> 3, ch = unit & 7;
      const int sch = ch ^ (row & 7);
      __builtin_amdgcn_global_load_lds(
          (const guint*)(qkv + ((size_t)b * SS + kt * 64 + row) * 3072 + 1024 + h * DHH + sch * 8),
          (luint*)(Ksh + unit * 8), 16, 0, 0);
      __builtin_amdgcn_global_load_lds(
          (const guint*)(vt + ((size_t)(h * DHH + row)) * MM + b * SS + kt * 64 + sch * 8),
          (luint*)(Vsh + unit * 8), 16, 0, 0);
    }
    __syncthreads();

    f32x4 st[4] = {};
    #pragma unroll
    for (int t = 0; t < 4; ++t) {
      const int row = t * 16 + qi;
      const int swz = (row & 7) << 4;
      short8v kf0 = *(const short8v*)(Ksh + row * 64 + (((g * 16) ^ swz) >> 1));
      short8v kf1 = *(const short8v*)(Ksh + row * 64 + (((64 + g * 16) ^ swz) >> 1));
      st[t] = __builtin_amdgcn_mfma_f32_16x16x32_bf16(kf0, qf0, st[t], 0, 0, 0);
      st[t] = __builtin_amdgcn_mfma_f32_16x16x32_bf16(kf1, qf1, st[t], 0, 0, 0);
    }

    if (kt == qt) {
      #pragma unroll
      for (int t = 0; t < 4; ++t)
        #pragma unroll
        for (int r = 0; r < 4; ++r)
          if (t * 16 + 4 * g + r > qloc) st[t][r] = -1e30f;
    }

    float mt = st[0][0];
    #pragma unroll
    for (int t = 0; t < 4; ++t)
      #pragma unroll
      for (int r = 0; r < 4; ++r) mt = fmaxf(mt, st[t][r]);
    mt = fmaxf(mt, __shfl_xor(mt, 16));
    mt = fmaxf(mt, __shfl_xor(mt, 32));
    const float mnew = fmaxf(mrow, mt * 0.125f);
    const float corr = __expf(mrow - mnew);
    float pl = 0.f;
    #pragma unroll
    for (int t = 0; t < 4; ++t) {
      #pragma unroll
      for (int r2 = 0; r2 < 2; ++r2) {
        float plo = __expf(fmaf(st[t][2 * r2], 0.125f, -mnew));
        float phi = __expf(fmaf(st[t][2 * r2 + 1], 0.125f, -mnew));
        pl += plo + phi;
        Plds[wave][qi * 41 + 8 * t + 2 * g + r2] =
            (unsigned)f2bf(plo) | ((unsigned)f2bf(phi) << 16);
      }
    }
    pl += __shfl_xor(pl, 16);
    pl += __shfl_xor(pl, 32);
    lrow = lrow * corr + pl;
    mrow = mnew;

    if (g == 0) bcast[wave][qi] = corr;
    float c0 = bcast[wave][g * 4 + 0];
    float c1 = bcast[wave][g * 4 + 1];
    float c2 = bcast[wave][g * 4 + 2];
    float c3 = bcast[wave][g * 4 + 3];
    #pragma unroll
    for (int dvt = 0; dvt < 4; ++dvt) {
      oacc[dvt][0] *= c0; oacc[dvt][1] *= c1;
      oacc[dvt][2] *= c2; oacc[dvt][3] *= c3;
    }

    union U8 { unsigned u[4]; short8v s8; };
    U8 pa0, pa1;
    #pragma unroll
    for (int c = 0; c < 4; ++c) {
      pa0.u[c] = Plds[wave][qi * 41 + g * 4 + c];
      pa1.u[c] = Plds[wave][qi * 41 + 16 + g * 4 + c];
    }
    #pragma unroll
    for (int dvt = 0; dvt < 4; ++dvt) {
      const int row = dvt * 16 + qi;
      const int swz = (row & 7) << 4;
      short8v v0 = *(const short8v*)(Vsh + row * 64 + (((g * 16) ^ swz) >> 1));
      short8v v1 = *(const short8v*)(Vsh + row * 64 + (((64 + g * 16) ^ swz) >> 1));
      oacc[dvt] = __builtin_amdgcn_mfma_f32_16x16x32_bf16(pa0.s8, v0, oacc[dvt], 0, 0, 0);
      oacc[dvt] = __builtin_amdgcn_mfma_f32_16x16x32_bf16(pa1.s8, v1, oacc[dvt], 0, 0, 0);
    }
  }

  if (g == 0) bcast[wave][qi] = 1.f / lrow;
  float i0 = bcast[wave][g * 4 + 0];
  float i1 = bcast[wave][g * 4 + 1];
  float i2 = bcast[wave][g * 4 + 2];
  float i3 = bcast[wave][g * 4 + 3];
  #pragma unroll
  for (int dvt = 0; dvt < 4; ++dvt) {
    const int col = h * DHH + dvt * 16 + qi;
    o[((size_t)b * SS + q0w + g * 4 + 0) * DD + col] = f2bf(oacc[dvt][0] * i0);
    o[((size_t)b * SS + q0w + g * 4 + 1) * DD + col] = f2bf(oacc[dvt][1] * i1);
    o[((size_t)b * SS + q0w + g * 4 + 2) * DD + col] = f2bf(oacc[dvt][2] * i2);
    o[((size_t)b * SS + q0w + g * 4 + 3) * DD + col] = f2bf(oacc[dvt][3] * i3);
  }
}

// ---------------------------------------------------------------------------
extern "C" void kernel_launch(void* const* d_in, const int* in_sizes, int n_in,
                              void* d_out, int out_size, void* d_ws, size_t ws_size,
                              hipStream_t stream) {
  const int* idx = (const int*)d_in[0];
  const float* tok_emb = (const float*)d_in[1];
  const float* pos_emb = (const float*)d_in[2];
  const float* ln1_s = (const float*)d_in[3];
  const float* ln1_b = (const float*)d_in[4];
  const float* wq = (const float*)d_in[5];
  const float* wk = (const float*)d_in[6];
  const float* wv = (const float*)d_in[7];
  const float* wproj = (const float*)d_in[8];
  const float* ln2_s = (const float*)d_in[9];
  const float* ln2_b = (const float*)d_in[10];
  const float* w1 = (const float*)d_in[11];
  const float* b1 = (const float*)d_in[12];
  const float* w2 = (const float*)d_in[13];
  const float* b2 = (const float*)d_in[14];
  const float* lnf_s = (const float*)d_in[15];
  const float* lnf_b = (const float*)d_in[16];
  const float* lm_w = (const float*)d_in[17];
  const float* lm_b = (const float*)d_in[18];

  const size_t MD = (size_t)MM * DD;

  // d_out scratch (~277 MB of 524 MB; all dead before the LM GEMM writes d_out)
  u16* sc0 = (u16*)d_out;
  u16* BTqkv = sc0;                                  // LL x [3072][1024]
  u16* BTp = BTqkv + (size_t)LL * 3072 * DD;
  u16* BTw1 = BTp + (size_t)LL * DD * DD;
  u16* BTw2 = BTw1 + (size_t)LL * DD * 4 * DD;
  u16* qkvb = BTw2 + (size_t)LL * DD * 4 * DD;       // [M][3072]
  u16* vtb = qkvb + (size_t)MM * 3072;               // [1024][4096]
  u16* ob = vtb + MD;
  u16* tmp = ob + MD;                                // [M][4096]

  // d_ws: x fp32 (16MB) + h bf16 (8MB) + BT(lm_w) bf16 (65.5MB) if room
  float* x = (float*)d_ws;
  u16* h = (u16*)((char*)d_ws + MD * 4);
  u16* BTlm = (u16*)((char*)d_ws + MD * 4 + MD * 2);
  const bool big_ws = ws_size >= (MD * 4 + MD * 2 + (size_t)VV * DD * 2);

  const dim3 blk(256);

  convT_kernel<true><<<dim3(DD / 32, DD / 32, LL), blk, 0, stream>>>(
      wq, BTqkv, DD, DD, (size_t)3072 * DD);
  convT_kernel<true><<<dim3(DD / 32, DD / 32, LL), blk, 0, stream>>>(
      wk, BTqkv + (size_t)DD * DD, DD, DD, (size_t)3072 * DD);
  convT_kernel<true><<<dim3(DD / 32, DD / 32, LL), blk, 0, stream>>>(
      wv, BTqkv + (size_t)2 * DD * DD, DD, DD, (size_t)3072 * DD);
  convT_kernel<false><<<dim3(DD / 32, DD / 32, LL), blk, 0, stream>>>(
      wproj, BTp, DD, DD, (size_t)DD * DD);
  convT_kernel<false><<<dim3(4 * DD / 32, DD / 32, LL), blk, 0, stream>>>(
      w1, BTw1, DD, 4 * DD, (size_t)DD * 4 * DD);
  convT_kernel<false><<<dim3(DD / 32, 4 * DD / 32, LL), blk, 0, stream>>>(
      w2, BTw2, 4 * DD, DD, (size_t)4 * DD * DD);
  if (big_ws)
    convT_kernel<false><<<dim3(VV / 32, DD / 32, 1), blk, 0, stream>>>(
        lm_w, BTlm, DD, VV, (size_t)VV * DD);

  embed_kernel<<<(MM * DD / 4 + 255) / 256, blk, 0, stream>>>(idx, tok_emb, pos_emb, x);

  for (int l = 0; l < LL; ++l) {
    ln_bf16_kernel<<<MM, blk, 0, stream>>>(x, ln1_s + l * DD, ln1_b + l * DD, h);
    // Fused Q+K+V (pipelined 256^2): C = h @ [Wq|Wk|Wv], N=3072
    gemm8<false, false, false, true, false><<<dim3((MM / 256) * (3072 / 256)), dim3(512), 0, stream>>>(
        h, BTqkv + (size_t)l * 3072 * DD, nullptr, nullptr, qkvb, MM, 3072, DD);
    transpose_v<<<dim3(MM / 32, DD / 32), blk, 0, stream>>>(qkvb, vtb);
    attn_mfma<<<dim3(SS / 64, HH, BB), blk, 0, stream>>>(qkvb, vtb, ob);
    gemm_mfma<false, false, true, false><<<dim3(MM / 128, DD / 128), blk, 0, stream>>>(
        ob, BTp + (size_t)l * DD * DD, nullptr, x, x, MM, DD, DD);
    ln_bf16_kernel<<<MM, blk, 0, stream>>>(x, ln2_s + l * DD, ln2_b + l * DD, h);
    // MLP1 (pipelined 256^2, NT store on tmp)
    gemm8<true, true, false, true, true><<<dim3((MM / 256) * (4 * DD / 256)), dim3(512), 0, stream>>>(
        h, BTw1 + (size_t)l * DD * 4 * DD, b1 + (size_t)l * 4 * DD, nullptr, tmp,
        MM, 4 * DD, DD);
    gemm_mfma<true, false, true, false><<<dim3(MM / 128, DD / 128), blk, 0, stream>>>(
        tmp, BTw2 + (size_t)l * 4 * DD * DD, b2 + (size_t)l * DD, x, x, MM, DD, 4 * DD);
  }

  ln_bf16_kernel<<<MM, blk, 0, stream>>>(x, lnf_s, lnf_b, h);
  if (big_ws) {
    // LM head (pipelined 256^2, NT store on the 524 MB fp32 output)
    gemm8<true, false, false, false, true><<<dim3((MM / 256) * (VV / 256)), dim3(512), 0, stream>>>(
        h, BTlm, lm_b, nullptr, (float*)d_out, MM, VV, DD);
  } else {
    gemm_fb<<<dim3(VV / 64, MM / 64), blk, 0, stream>>>(
        h, lm_w, lm_b, (float*)d_out, MM, VV, DD);
  }
}